// Round 14
// baseline (554.708 us; speedup 1.0000x reference)
//
#include <hip/hip_runtime.h>
#include <hip/hip_fp16.h>
#include <math.h>

// ---------------- sizes ----------------
#define B32   32
#define OCLS  102
#define NCAPS 2592

// ---------------- ws map (floats) -- ws is 616 MB; flat, no overlays ----
#define OFF_FEAT   0u               // feat2[b][h][co][w36]: 10,027,008
#define OFF_C1WT   10027008u        // bf16 conv1 pack: 49,152
#define OFF_PCWQ   10076160u        // fp8 pc pack: 1,703,936
#define OFF_PCP    11780096u        // fp16 partials 16 slices: 5,308,416
#define OFF_WQ2    17088512u        // fp8 W pack [o][n][d][i]: 33,841,152 B
#define OFF_WQ     25555456u        // fp8 W pack [o][n][i][d]: 33,841,152 B
#define OFF_U2     34022400u        // 663,552
#define OFF_CT     34685952u        // fp16 E[o][n][b]: 4,230,144
#define OFF_DEN    38916096u        // f32 den[n][b]: 82,944
#define OFF_S      38999040u        // 52,224
#define OFF_V0     39051264u
#define OFF_V1     39103488u
#define OFF_VSQ    39155712u        // fp8 vsum x1024
#define OFF_H2T    39185152u
#define OFF_FC3P   39217920u        // 4,816,896 -> end 44,034,816 (176MB < 616MB)

typedef __attribute__((ext_vector_type(8))) short short8;
typedef __attribute__((ext_vector_type(4))) float f32x4;
typedef long long i64;

__device__ __forceinline__ unsigned short f2b(float f) {
  union { float f; unsigned u; } v; v.f = f;
  unsigned r = v.u + 0x7fffu + ((v.u >> 16) & 1u);
  return (unsigned short)(r >> 16);
}

// float -> OCP e4m3fn (RNE, flush<2^-6, clamp) -- software fallback
__device__ __forceinline__ unsigned f2q_fast(float x) {
  union { float f; unsigned u; } v; v.f = x;
  unsigned s = (v.u >> 24) & 0x80u;
  unsigned au = v.u & 0x7fffffffu;
  if (au < 0x3c800000u) return s;
  if (au >= 0x43e00000u) return s | 0x7eu;
  unsigned r = au + 0x7ffffu + ((au >> 20) & 1u);
  unsigned e = (r >> 23) - 120u;
  unsigned m = (r >> 20) & 7u;
  return s | (e << 3) | m;
}

__device__ __forceinline__ unsigned fp8pair(float a, float b) {
#if __has_builtin(__builtin_amdgcn_cvt_pk_fp8_f32)
  return (unsigned)__builtin_amdgcn_cvt_pk_fp8_f32(a, b, 0, false) & 0xffffu;
#else
  return f2q_fast(a) | (f2q_fast(b) << 8);
#endif
}

__device__ __forceinline__ float rcpf(float x) {
#if __has_builtin(__builtin_amdgcn_rcpf)
  return __builtin_amdgcn_rcpf(x);
#else
  return 1.0f / x;
#endif
}

// ---------------- merged weight-pack kernel ----------------
// [0,256): conv1_w -> bf16 C1WB   [256,512): pc_w -> fp8 PCWQ
// [512,8774): W -> fp8 Wq2. Lane-contiguous: load instr k covers a contiguous
// 1KB window (16B/lane); store 4B/lane in 256B wave-runs.
__global__ __launch_bounds__(256) void k_pack(const float* __restrict__ conv1_w,
                                              const float* __restrict__ pc_w,
                                              const float* __restrict__ W,
                                              unsigned short* __restrict__ C1WB,
                                              unsigned char* __restrict__ PCWQ,
                                              unsigned char* __restrict__ Wq2) {
  int bb = blockIdx.x;
  int t = threadIdx.x;
  if (bb < 256) {
    if (t < 128) {
#pragma unroll
      for (int ci = 0; ci < 3; ++ci) {
        float v = (t < 121) ? conv1_w[bb * 363 + ci * 121 + t] : 0.f;
        C1WB[(ci * 256 + bb) * 128 + t] = f2b(v);
      }
    }
  } else if (bb < 512) {
    int co = bb - 256;
    for (int e = t; e < 20736; e += 256) {
      int ci = e / 81, tap = e - ci * 81;
      PCWQ[(size_t)ci * 26624 + co * 104 + tap] =
          (unsigned char)f2q_fast(pc_w[(size_t)co * 20736 + e] * 64.f);
    }
    for (int tap = 81; tap < 104; ++tap)
      PCWQ[(size_t)t * 26624 + co * 104 + tap] = 0;
  } else {
    size_t base = (size_t)(bb - 512) * 1024;  // f32x4 units
    const f32x4* src = (const f32x4*)W;
    unsigned* dst = (unsigned*)Wq2;
#pragma unroll
    for (int k = 0; k < 4; ++k) {
      size_t idx = base + (size_t)k * 256 + t;
      f32x4 v = src[idx];
      dst[idx] = fp8pair(v[0] * 64.f, v[1] * 64.f) |
                 (fp8pair(v[2] * 64.f, v[3] * 64.f) << 16);
    }
  }
}

// ---------------- Wq2 -> Wq byte transpose ([d][i] -> [i][d] within 128B rows) ----
// [0,8262): 32 rows/block via 4KB LDS.  [8262,8313): zero S.
__global__ __launch_bounds__(256) void k_tr(const unsigned char* __restrict__ Wq2,
                                            unsigned char* __restrict__ Wq,
                                            float* __restrict__ S) {
  __shared__ unsigned char sq[32 * 128];
  int bb = blockIdx.x;
  int t = threadIdx.x;
  if (bb < 8262) {
    size_t base = (size_t)bb * 4096;
    uint4 q = *(const uint4*)(Wq2 + base + (size_t)t * 16);
    unsigned w[4] = {q.x, q.y, q.z, q.w};
    int r = t >> 3, seg = t & 7;
#pragma unroll
    for (int e = 0; e < 16; ++e) {
      int p = seg * 16 + e, d = p >> 3, i = p & 7;
      sq[r * 128 + i * 16 + d] = (unsigned char)((w[e >> 2] >> ((e & 3) * 8)) & 0xffu);
    }
    __syncthreads();
    *(uint4*)(Wq + base + (size_t)t * 16) = ((const uint4*)sq)[t];
  } else {
    int idx = (bb - 8262) * 1024 + t * 4;  // 51*1024 = 52224
    *(float4*)(S + idx) = make_float4(0.f, 0.f, 0.f, 0.f);
  }
}

// ---------------- conv1 via bf16 MFMA, co-split x2 ----------------
__global__ __launch_bounds__(256) void k_c1m(const float* __restrict__ x,
                                             const unsigned short* __restrict__ C1WB,
                                             const float* __restrict__ bias,
                                             float* __restrict__ feat2) {
  __shared__ unsigned short sh[48 * 128 + 128 * 128];
  unsigned short* lA = sh;
  unsigned short* lB = sh + 48 * 128;
  float* obuf = (float*)(sh + 48 * 128);

  int bx = blockIdx.x;
  int hf = blockIdx.y;  // co half
  int b = bx / 34, ho = bx % 34;
  int t = threadIdx.x;
  int lane = t & 63, wv = t >> 6;
  int l15 = lane & 15, lh = lane >> 4;
  int rx = l15 & 7;

  {
    uint4 zz = make_uint4(0, 0, 0, 0);
    uint4* z = (uint4*)lA;
    for (int i = t; i < 48 * 128 / 8; i += 256) z[i] = zz;
  }
  __syncthreads();

  f32x4 acc[3][2];
#pragma unroll
  for (int mf = 0; mf < 3; ++mf)
#pragma unroll
    for (int nf = 0; nf < 2; ++nf) acc[mf][nf] = (f32x4){0.f, 0.f, 0.f, 0.f};

#pragma unroll 1
  for (int ci = 0; ci < 3; ++ci) {
    {
      const uint4* Bsrc = (const uint4*)(C1WB + ci * 32768 + hf * 16384);
#pragma unroll
      for (int i = 0; i < 8; ++i) {
        int f = i * 256 + t;
        int row = f >> 4, cu = f & 15;
        ((uint4*)lB)[row * 16 + (cu ^ (row & 7))] = Bsrc[f];
      }
    }
    for (int tk = t; tk < 374; tk += 256) {
      int kh = tk / 34, wo = tk - kh * 34;
      const float* src = x + ((size_t)(b * 3 + ci) * 112 + ho * 3 + kh) * 112 + wo * 3;
#pragma unroll
      for (int j = 0; j < 11; ++j) {
        int tap = kh * 11 + j;
        int cu = tap >> 3;
        lA[wo * 128 + (((cu ^ (wo & 7)) << 3) | (tap & 7))] = f2b(src[j]);
      }
    }
    __syncthreads();

#pragma unroll
    for (int s = 0; s < 4; ++s) {
      int cub = ((s * 4 + lh) ^ rx) << 3;
      short8 a0 = *(const short8*)(lA + (0 + l15) * 128 + cub);
      short8 a1 = *(const short8*)(lA + (16 + l15) * 128 + cub);
      short8 a2 = *(const short8*)(lA + (32 + l15) * 128 + cub);
      short8 b0 = *(const short8*)(lB + (wv * 32 + 0 + l15) * 128 + cub);
      short8 b1 = *(const short8*)(lB + (wv * 32 + 16 + l15) * 128 + cub);
      acc[0][0] = __builtin_amdgcn_mfma_f32_16x16x32_bf16(a0, b0, acc[0][0], 0, 0, 0);
      acc[0][1] = __builtin_amdgcn_mfma_f32_16x16x32_bf16(a0, b1, acc[0][1], 0, 0, 0);
      acc[1][0] = __builtin_amdgcn_mfma_f32_16x16x32_bf16(a1, b0, acc[1][0], 0, 0, 0);
      acc[1][1] = __builtin_amdgcn_mfma_f32_16x16x32_bf16(a1, b1, acc[1][1], 0, 0, 0);
      acc[2][0] = __builtin_amdgcn_mfma_f32_16x16x32_bf16(a2, b0, acc[2][0], 0, 0, 0);
      acc[2][1] = __builtin_amdgcn_mfma_f32_16x16x32_bf16(a2, b1, acc[2][1], 0, 0, 0);
    }
    __syncthreads();
  }

  float bv[2];
#pragma unroll
  for (int nf = 0; nf < 2; ++nf) bv[nf] = bias[hf * 128 + wv * 32 + nf * 16 + l15];
#pragma unroll
  for (int mf = 0; mf < 3; ++mf)
#pragma unroll
    for (int nf = 0; nf < 2; ++nf)
#pragma unroll
      for (int r = 0; r < 4; ++r) {
        int wo = mf * 16 + lh * 4 + r;
        if (wo < 36)
          obuf[(wv * 32 + nf * 16 + l15) * 36 + wo] = fmaxf(acc[mf][nf][r] + bv[nf], 0.f);
      }
  __syncthreads();
  float4* dst = (float4*)(feat2 + (size_t)bx * 9216 + hf * 4608);
  const float4* srcb = (const float4*)obuf;
  for (int i = t; i < 1152; i += 256) dst[i] = srcb[i];
}

// ---------------- pc conv gather (fp8, HW cvt pairs) ----------------
__device__ __forceinline__ void pc_gather8(const float* __restrict__ feat2,
                                           unsigned char* __restrict__ dstbuf,
                                           int mb, int ci, int t) {
  for (int task = t; task < 576; task += 256) {
    int m = task / 9, kh = task - m * 9;
    int gm = mb * 64 + m;
    if (gm < 2592) {
      int b = gm / 81, p = gm - b * 81;
      int ho = p / 9, wo = p - ho * 9;
      const float* src = feat2 + ((size_t)(b * 34 + ho * 3 + kh) * 256 + ci) * 36 + wo * 3;
      unsigned char* dst = dstbuf + m * 104 + kh * 9;
      unsigned p01 = fp8pair(src[0], src[1]);
      unsigned p23 = fp8pair(src[2], src[3]);
      unsigned p45 = fp8pair(src[4], src[5]);
      unsigned p67 = fp8pair(src[6], src[7]);
      unsigned p8  = fp8pair(src[8], 0.f);
      dst[0] = p01; dst[1] = p01 >> 8;
      dst[2] = p23; dst[3] = p23 >> 8;
      dst[4] = p45; dst[5] = p45 >> 8;
      dst[6] = p67; dst[7] = p67 >> 8;
      dst[8] = p8;
    }
  }
}

// ---------------- primary caps conv: fp8 MFMA, kc=16, fp16 partials ----------------
__global__ __launch_bounds__(256, 3) void k_pc4(const float* __restrict__ feat2,
                                                const unsigned char* __restrict__ PCWQ,
                                                __half* __restrict__ pcp) {
  __shared__ unsigned char lA[2][64 * 104];

  int mb = blockIdx.x, kc = blockIdx.y;  // (41, 16)
  int t = threadIdx.x;
  int lane = t & 63, wv = t >> 6;
  int l15 = lane & 15, lh = lane >> 4;

  {
    uint4 zz = make_uint4(0, 0, 0, 0);
    uint4* z = (uint4*)lA;
    for (int i = t; i < 2 * 64 * 104 / 16; i += 256) z[i] = zz;
  }
  __syncthreads();
  pc_gather8(feat2, lA[0], mb, kc * 16, t);
  __syncthreads();

  f32x4 acc[4][4];
#pragma unroll
  for (int mf = 0; mf < 4; ++mf)
#pragma unroll
    for (int nf = 0; nf < 4; ++nf) acc[mf][nf] = (f32x4){0.f, 0.f, 0.f, 0.f};

#pragma unroll 1
  for (int cil = 0; cil < 16; ++cil) {
    int ci = kc * 16 + cil;
    int cur = cil & 1;

    i64 bfr[4][3];
    const unsigned char* Bbase = PCWQ + (size_t)ci * 26624 + (wv * 64 + l15) * 104 + lh * 8;
#pragma unroll
    for (int nf = 0; nf < 4; ++nf)
#pragma unroll
      for (int s = 0; s < 3; ++s)
        bfr[nf][s] = *(const i64*)(Bbase + nf * 16 * 104 + s * 32);

    if (cil < 15) pc_gather8(feat2, lA[cur ^ 1], mb, ci + 1, t);

    const unsigned char* arow = lA[cur] + l15 * 104 + lh * 8;
#pragma unroll
    for (int s = 0; s < 3; ++s) {
      i64 a0 = *(const i64*)(arow + s * 32);
      i64 a1 = *(const i64*)(arow + 16 * 104 + s * 32);
      i64 a2 = *(const i64*)(arow + 32 * 104 + s * 32);
      i64 a3 = *(const i64*)(arow + 48 * 104 + s * 32);
      acc[0][0] = __builtin_amdgcn_mfma_f32_16x16x32_fp8_fp8(a0, bfr[0][s], acc[0][0], 0, 0, 0);
      acc[0][1] = __builtin_amdgcn_mfma_f32_16x16x32_fp8_fp8(a0, bfr[1][s], acc[0][1], 0, 0, 0);
      acc[0][2] = __builtin_amdgcn_mfma_f32_16x16x32_fp8_fp8(a0, bfr[2][s], acc[0][2], 0, 0, 0);
      acc[0][3] = __builtin_amdgcn_mfma_f32_16x16x32_fp8_fp8(a0, bfr[3][s], acc[0][3], 0, 0, 0);
      acc[1][0] = __builtin_amdgcn_mfma_f32_16x16x32_fp8_fp8(a1, bfr[0][s], acc[1][0], 0, 0, 0);
      acc[1][1] = __builtin_amdgcn_mfma_f32_16x16x32_fp8_fp8(a1, bfr[1][s], acc[1][1], 0, 0, 0);
      acc[1][2] = __builtin_amdgcn_mfma_f32_16x16x32_fp8_fp8(a1, bfr[2][s], acc[1][2], 0, 0, 0);
      acc[1][3] = __builtin_amdgcn_mfma_f32_16x16x32_fp8_fp8(a1, bfr[3][s], acc[1][3], 0, 0, 0);
      acc[2][0] = __builtin_amdgcn_mfma_f32_16x16x32_fp8_fp8(a2, bfr[0][s], acc[2][0], 0, 0, 0);
      acc[2][1] = __builtin_amdgcn_mfma_f32_16x16x32_fp8_fp8(a2, bfr[1][s], acc[2][1], 0, 0, 0);
      acc[2][2] = __builtin_amdgcn_mfma_f32_16x16x32_fp8_fp8(a2, bfr[2][s], acc[2][2], 0, 0, 0);
      acc[2][3] = __builtin_amdgcn_mfma_f32_16x16x32_fp8_fp8(a2, bfr[3][s], acc[2][3], 0, 0, 0);
      acc[3][0] = __builtin_amdgcn_mfma_f32_16x16x32_fp8_fp8(a3, bfr[0][s], acc[3][0], 0, 0, 0);
      acc[3][1] = __builtin_amdgcn_mfma_f32_16x16x32_fp8_fp8(a3, bfr[1][s], acc[3][1], 0, 0, 0);
      acc[3][2] = __builtin_amdgcn_mfma_f32_16x16x32_fp8_fp8(a3, bfr[2][s], acc[3][2], 0, 0, 0);
      acc[3][3] = __builtin_amdgcn_mfma_f32_16x16x32_fp8_fp8(a3, bfr[3][s], acc[3][3], 0, 0, 0);
    }
    __syncthreads();
  }

#pragma unroll
  for (int mf = 0; mf < 4; ++mf) {
    int gm = mb * 64 + mf * 16 + lh * 4;
    if (gm < 2592) {
      __half* dst = pcp + (size_t)kc * 663552 + (size_t)gm * 256 + wv * 64 + l15;
#pragma unroll
      for (int nf = 0; nf < 4; ++nf)
#pragma unroll
        for (int r = 0; r < 4; ++r)
          dst[(size_t)r * 256 + nf * 16] = __float2half(acc[mf][nf][r]);
    }
  }
}

// ---------------- fused transpose-reduce-squash: pcp(16 fp16 slices) -> u2 ----------------
__global__ __launch_bounds__(256) void k_rs(const __half* __restrict__ pcp,
                                            const float* __restrict__ pcb,
                                            float* __restrict__ u2) {
  __shared__ float tile[81 * 17];
  int b = blockIdx.x;    // 32
  int cog = blockIdx.y;  // 16
  int c0 = cog * 16;
  int t = threadIdx.x;

  for (int e = t; e < 1296; e += 256) {
    int p = e >> 4, col = e & 15;
    const __half* base = pcp + (size_t)(b * 81 + p) * 256 + c0 + col;
    float s = 0.f;
#pragma unroll
    for (int c = 0; c < 16; ++c) s += __half2float(base[(size_t)c * 663552]);
    tile[p * 17 + col] = pcb[c0 + col] + s * 0.015625f;  // /64 (W x64)
  }
  __syncthreads();

  if (t < 162) {
    float v[8];
    float sq = 0.f;
#pragma unroll
    for (int i = 0; i < 8; ++i) {
      int g = t * 8 + i;
      int col = g / 81, p = g - col * 81;
      v[i] = tile[p * 17 + col];
      sq += v[i] * v[i];
    }
    float sc = (sq / (1.f + sq)) / sqrtf(sq + 1e-8f);
    int n = cog * 162 + t;
    float4* dst = (float4*)(u2 + ((size_t)b * 2592 + n) * 8);
    dst[0] = make_float4(v[0] * sc, v[1] * sc, v[2] * sc, v[3] * sc);
    dst[1] = make_float4(v[4] * sc, v[5] * sc, v[6] * sc, v[7] * sc);
  }
}

// ---------------- routing kernel A3 (fp8 MFMA, o-split x3): E + partial den ----------------
__global__ __launch_bounds__(128) void k_A3(const unsigned char* __restrict__ Wq,
                                            const float* __restrict__ u2,
                                            const unsigned char* __restrict__ vq,
                                            __half* __restrict__ cT,
                                            float* __restrict__ den) {
  int nb = blockIdx.x;   // 648
  int ch = blockIdx.y;   // 3
  int o0 = ch * 34;
  int t = threadIdx.x, wv = t >> 6, lane = t & 63;
  int l15 = lane & 15, g = lane >> 4;
  int n0 = nb * 4 + 2 * wv;
  int nl = g >> 1, ih = (g & 1) * 4;

  float4 u0 = *(const float4*)(u2 + (((size_t)l15 * 2592 + n0 + nl) * 8 + ih));
  float4 u1 = *(const float4*)(u2 + (((size_t)(l15 + 16) * 2592 + n0 + nl) * 8 + ih));

  int nlA = l15 >> 3, iA = l15 & 7;
  const unsigned char* Ap = Wq + (((size_t)(n0 + nlA)) * 8 + iA) * 16 + (g & 1) * 8 +
                            (size_t)o0 * 331776;
  const unsigned char* B0p = vq + (size_t)l15 * 16 + (g & 1) * 8 + (size_t)o0 * 512;
  bool act = (g < 2);

  float den0 = 0.f, den1 = 0.f;
#pragma unroll 2
  for (int oo = 0; oo < 34; ++oo) {
    i64 a = 0, b0 = 0, b1 = 0;
    if (act) {
      a  = *(const i64*)(Ap + (size_t)oo * 331776);
      b0 = *(const i64*)(B0p + (size_t)oo * 512);
      b1 = *(const i64*)(B0p + (size_t)oo * 512 + 256);
    }
    f32x4 d0 = {0.f, 0.f, 0.f, 0.f}, d1 = {0.f, 0.f, 0.f, 0.f};
    d0 = __builtin_amdgcn_mfma_f32_16x16x32_fp8_fp8(a, b0, d0, 0, 0, 0);
    d1 = __builtin_amdgcn_mfma_f32_16x16x32_fp8_fp8(a, b1, d1, 0, 0, 0);
    float p0 = d0[0] * u0.x + d0[1] * u0.y + d0[2] * u0.z + d0[3] * u0.w;
    float p1 = d1[0] * u1.x + d1[1] * u1.y + d1[2] * u1.z + d1[3] * u1.w;
    p0 += __shfl_xor(p0, 16);
    p1 += __shfl_xor(p1, 16);
    p0 *= 1.52587890625e-05f;  // / (64 * 1024)
    p1 *= 1.52587890625e-05f;
    float e0 = __expf(p0), e1 = __expf(p1);
    den0 += e0; den1 += e1;
    if ((g & 1) == 0) {
      __half* dst = cT + ((size_t)(o0 + oo) * 2592 + n0 + nl) * 32 + l15;
      dst[0]  = __float2half(e0);
      dst[16] = __float2half(e1);
    }
  }
  if ((g & 1) == 0) {
    atomicAdd(den + (n0 + nl) * 32 + l15, den0);
    atomicAdd(den + (n0 + nl) * 32 + l15 + 16, den1);
  }
}

// ---------------- routing kernel B (fp8 MFMA): s = sum (E/den)*xhat ----------------
__device__ __forceinline__ i64 cu_pack8(float c, float4 a, float4 b) {
  union { unsigned u[2]; i64 v; } r;
  r.u[0] = fp8pair(c * a.x, c * a.y) | (fp8pair(c * a.z, c * a.w) << 16);
  r.u[1] = fp8pair(c * b.x, c * b.y) | (fp8pair(c * b.z, c * b.w) << 16);
  return r.v;
}

template <bool HASC>
__global__ __launch_bounds__(256) void k_B3(const unsigned char* __restrict__ Wq2,
                                            const float* __restrict__ u2,
                                            const __half* __restrict__ cT,
                                            const float* __restrict__ den,
                                            float* __restrict__ s) {
  int o = blockIdx.x, kc = blockIdx.y;  // (102, 12)
  int t = threadIdx.x, lane = t & 63, wv = t >> 6;
  int l15 = lane & 15, h = lane >> 4;

  f32x4 acc0 = {0.f, 0.f, 0.f, 0.f}, acc1 = {0.f, 0.f, 0.f, 0.f};

#pragma unroll 1
  for (int st = wv; st < 54; st += 4) {
    int n = kc * 216 + st * 4 + h;
    i64 aq = *(const i64*)(Wq2 + (((size_t)o * 2592 + n) * 16 + l15) * 8);

    const float4* u0p = (const float4*)(u2 + ((size_t)l15 * 2592 + n) * 8);
    float4 u0a = u0p[0], u0b = u0p[1];
    const float4* u1p = (const float4*)(u2 + ((size_t)(l15 + 16) * 2592 + n) * 8);
    float4 u1a = u1p[0], u1b = u1p[1];

    float c0 = 16.0f, c1 = 16.0f;
    if (HASC) {
      const __half* cp = cT + ((size_t)o * 2592 + n) * 32;
      float i0 = rcpf(den[n * 32 + l15]);
      float i1 = rcpf(den[n * 32 + l15 + 16]);
      c0 = 16.0f * __half2float(cp[l15]) * i0;
      c1 = 16.0f * __half2float(cp[l15 + 16]) * i1;
    }
    i64 b0 = cu_pack8(c0, u0a, u0b);
    i64 b1 = cu_pack8(c1, u1a, u1b);

    acc0 = __builtin_amdgcn_mfma_f32_16x16x32_fp8_fp8(aq, b0, acc0, 0, 0, 0);
    acc1 = __builtin_amdgcn_mfma_f32_16x16x32_fp8_fp8(aq, b1, acc1, 0, 0, 0);
  }

#pragma unroll
  for (int r = 0; r < 4; ++r) {
    atomicAdd(s + ((size_t)l15 * 102 + o) * 16 + h * 4 + r, acc0[r]);
    atomicAdd(s + ((size_t)(l15 + 16) * 102 + o) * 16 + h * 4 + r, acc1[r]);
  }
}

// ---------------- squash v; optional fp8 vsum; optional S re-zero + den zero ----------------
__global__ void k_R(const float* __restrict__ s, float scale,
                    float* __restrict__ vout, const float* __restrict__ addin,
                    unsigned char* __restrict__ vsq, float* __restrict__ szero,
                    float* __restrict__ dzero) {
  int t = blockIdx.x * 256 + threadIdx.x;  // grid 13*256 = 3328
  if (dzero) {
    for (int i = t; i < 82944; i += 3328) dzero[i] = 0.f;
  }
  if (t >= 3264) return;
  const float* sp = s + t * 16;
  float r[16];
  float sq = 0.f;
#pragma unroll
  for (int d = 0; d < 16; ++d) {
    r[d] = sp[d] * scale;
    sq += r[d] * r[d];
  }
  if (szero) {
#pragma unroll
    for (int d = 0; d < 16; ++d) szero[t * 16 + d] = 0.f;
  }
  float sc = (sq / (1.f + sq)) / sqrtf(sq + 1e-8f);
  float vv[16];
#pragma unroll
  for (int d = 0; d < 16; ++d) {
    vv[d] = r[d] * sc;
    vout[t * 16 + d] = vv[d];
  }
  if (vsq) {
    int b = t / 102, o = t - b * 102;
    float w[16];
#pragma unroll
    for (int d = 0; d < 16; ++d)
      w[d] = (addin ? (addin[t * 16 + d] + vv[d]) : vv[d]) * 1024.f;
    unsigned words[4];
#pragma unroll
    for (int q = 0; q < 4; ++q)
      words[q] = fp8pair(w[4 * q], w[4 * q + 1]) | (fp8pair(w[4 * q + 2], w[4 * q + 3]) << 16);
    *(uint4*)(vsq + ((size_t)o * 32 + b) * 16) =
        make_uint4(words[0], words[1], words[2], words[3]);
  }
}

// ---------------- fused fc1+fc2: block = bq (4 batch items), h1 in LDS ----------------
__global__ __launch_bounds__(512) void k_fc12(const float* __restrict__ v2,
                                              const int* __restrict__ tgt,
                                              const float* __restrict__ w1,
                                              const float* __restrict__ b1,
                                              const float* __restrict__ w2,
                                              const float* __restrict__ b2,
                                              float* __restrict__ h2T) {
  __shared__ float h1s[4][512];
  int bq = blockIdx.x;  // 8
  int t = threadIdx.x;  // 512
#pragma unroll
  for (int bi = 0; bi < 4; ++bi) {
    int b = bq * 4 + bi;
    int tb = tgt[b];
    float acc = b1[t];
    const float* vv = v2 + (b * 102 + tb) * 16;
    const float* wr = w1 + (tb * 16) * 512 + t;
#pragma unroll
    for (int d = 0; d < 16; ++d) acc += vv[d] * wr[d * 512];
    h1s[bi][t] = fmaxf(acc, 0.f);
  }
  __syncthreads();
  float a0[4], a1[4];
#pragma unroll
  for (int bi = 0; bi < 4; ++bi) { a0[bi] = b2[t]; a1[bi] = b2[t + 512]; }
  for (int k = 0; k < 512; ++k) {
    float w0 = w2[k * 1024 + t], w1v = w2[k * 1024 + t + 512];
#pragma unroll
    for (int bi = 0; bi < 4; ++bi) {
      float h = h1s[bi][k];
      a0[bi] += h * w0;
      a1[bi] += h * w1v;
    }
  }
  float4 o0, o1;
  o0.x = fmaxf(a0[0], 0.f); o0.y = fmaxf(a0[1], 0.f);
  o0.z = fmaxf(a0[2], 0.f); o0.w = fmaxf(a0[3], 0.f);
  o1.x = fmaxf(a1[0], 0.f); o1.y = fmaxf(a1[1], 0.f);
  o1.z = fmaxf(a1[2], 0.f); o1.w = fmaxf(a1[3], 0.f);
  *(float4*)(h2T + t * 32 + bq * 4) = o0;
  *(float4*)(h2T + (t + 512) * 32 + bq * 4) = o1;
}

__global__ void k_fc3a(const float* __restrict__ h2T, const float* __restrict__ w3,
                       float* __restrict__ p) {
  int j = blockIdx.x * 128 + threadIdx.x;
  int ky = blockIdx.y;
  float acc[32];
#pragma unroll
  for (int i = 0; i < 32; ++i) acc[i] = 0.f;
  int k0 = ky * 256;
  for (int k = k0; k < k0 + 256; ++k) {
    float wv = w3[(size_t)k * 37632 + j];
    const float4* hp = (const float4*)(h2T + k * 32);
#pragma unroll
    for (int q = 0; q < 8; ++q) {
      float4 h = hp[q];
      acc[q * 4 + 0] += h.x * wv; acc[q * 4 + 1] += h.y * wv;
      acc[q * 4 + 2] += h.z * wv; acc[q * 4 + 3] += h.w * wv;
    }
  }
#pragma unroll
  for (int i = 0; i < 32; ++i)
    p[((size_t)ky * 32 + i) * 37632 + j] = acc[i];
}

__global__ void k_fc3b(const float* __restrict__ p, const float* __restrict__ b3,
                       float* __restrict__ out) {
  int j = blockIdx.x * 256 + threadIdx.x;
  float bv = b3[j];
#pragma unroll 1
  for (int b = 0; b < 32; ++b) {
    float s = bv + p[(size_t)b * 37632 + j] + p[(size_t)(32 + b) * 37632 + j] +
              p[(size_t)(64 + b) * 37632 + j] + p[(size_t)(96 + b) * 37632 + j];
    out[52224 + (size_t)b * 37632 + j] = 1.0f / (1.0f + __expf(-s));
  }
}

// ---------------- host ----------------
extern "C" void kernel_launch(void* const* d_in, const int* in_sizes, int n_in,
                              void* d_out, int out_size, void* d_ws, size_t ws_size,
                              hipStream_t stream) {
  const float* x       = (const float*)d_in[0];
  const int*   targets = (const int*)d_in[1];
  const float* conv1_w = (const float*)d_in[2];
  const float* conv1_b = (const float*)d_in[3];
  const float* pc_w    = (const float*)d_in[4];
  const float* pc_b    = (const float*)d_in[5];
  const float* W       = (const float*)d_in[6];
  const float* fc1_w   = (const float*)d_in[7];
  const float* fc1_b   = (const float*)d_in[8];
  const float* fc2_w   = (const float*)d_in[9];
  const float* fc2_b   = (const float*)d_in[10];
  const float* fc3_w   = (const float*)d_in[11];
  const float* fc3_b   = (const float*)d_in[12];
  float* out = (float*)d_out;
  float* ws = (float*)d_ws;

  float* FEAT2 = ws + OFF_FEAT;
  unsigned short* C1WB = (unsigned short*)(ws + OFF_C1WT);
  unsigned char* PCWQ = (unsigned char*)(ws + OFF_PCWQ);
  __half* PCP = (__half*)(ws + OFF_PCP);
  unsigned char* WQ2 = (unsigned char*)(ws + OFF_WQ2);
  unsigned char* WQ  = (unsigned char*)(ws + OFF_WQ);
  float* U2   = ws + OFF_U2;
  __half* CT  = (__half*)(ws + OFF_CT);
  float* DEN  = ws + OFF_DEN;
  float* S    = ws + OFF_S;
  float* V0   = ws + OFF_V0;
  float* V1   = ws + OFF_V1;
  unsigned char* VSQ = (unsigned char*)(ws + OFF_VSQ);
  float* H2T  = ws + OFF_H2T;
  float* FC3P = ws + OFF_FC3P;

  // weight packs: stream Wq2 (lane-contiguous), then derive Wq from it (+S zero)
  k_pack<<<dim3(8774), 256, 0, stream>>>(conv1_w, pc_w, W, C1WB, PCWQ, WQ2);
  k_tr<<<dim3(8313), 256, 0, stream>>>(WQ2, WQ, S);

  // conv1 + relu (bf16 MFMA, co-split)
  k_c1m<<<dim3(1088, 2), 256, 0, stream>>>(x, C1WB, conv1_b, FEAT2);

  // primary caps conv + fused reduce/squash
  k_pc4<<<dim3(41, 16), 256, 0, stream>>>(FEAT2, PCWQ, PCP);
  k_rs<<<dim3(32, 16), 256, 0, stream>>>(PCP, pc_b, U2);

  // ---- routing ---- (scales: W x64, cu x16 -> /1024; vq x1024 -> logits /65536)
  k_B3<false><<<dim3(102, 12), 256, 0, stream>>>(WQ2, U2, nullptr, nullptr, S);
  k_R<<<dim3(13), 256, 0, stream>>>(S, 1.0f / (102.0f * 1024.0f), V0, nullptr, VSQ, S, DEN);

  k_A3<<<dim3(648, 3), 128, 0, stream>>>(WQ, U2, VSQ, CT, DEN);
  k_B3<true><<<dim3(102, 12), 256, 0, stream>>>(WQ2, U2, CT, DEN, S);
  k_R<<<dim3(13), 256, 0, stream>>>(S, 1.0f / 1024.0f, V1, V0, VSQ, S, DEN);  // vsq = v0+v1

  k_A3<<<dim3(648, 3), 128, 0, stream>>>(WQ, U2, VSQ, CT, DEN);
  k_B3<true><<<dim3(102, 12), 256, 0, stream>>>(WQ2, U2, CT, DEN, S);
  k_R<<<dim3(13), 256, 0, stream>>>(S, 1.0f / 1024.0f, out, nullptr, nullptr, nullptr, nullptr);

  // ---- reconstruction ----
  k_fc12<<<dim3(8), 512, 0, stream>>>(out, targets, fc1_w, fc1_b, fc2_w, fc2_b, H2T);
  k_fc3a<<<dim3(294, 4), 128, 0, stream>>>(H2T, fc3_w, FC3P);
  k_fc3b<<<dim3(147), 256, 0, stream>>>(FC3P, fc3_b, out);
}

// Round 15
// 549.170 us; speedup vs baseline: 1.0101x; 1.0101x over previous
//
#include <hip/hip_runtime.h>
#include <hip/hip_fp16.h>
#include <math.h>

// ---------------- sizes ----------------
#define B32   32
#define OCLS  102
#define NCAPS 2592

// ---------------- ws map (floats) -- ws is 616 MB; flat, no overlays ----
#define OFF_FEAT   0u               // feat2[b][h][co][w36] bf16: 1088*9216 ush
#define OFF_C1WT   10027008u        // bf16 conv1 pack: 49,152
#define OFF_PCWQ   10076160u        // fp8 pc pack: 1,703,936
#define OFF_PCP    11780096u        // fp16 partials 16 slices: 5,308,416
#define OFF_WQ2    17088512u        // fp8 W pack [o][n][d][i]
#define OFF_WQ     25555456u        // fp8 W pack [o][n][i][d]
#define OFF_U2     34022400u        // 663,552
#define OFF_CT     34685952u        // fp16 E[o][n][b]: 4,230,144
#define OFF_DEN    38916096u        // f32 den[n][b]: 82,944
#define OFF_S      38999040u        // 52,224
#define OFF_V0     39051264u
#define OFF_V1     39103488u
#define OFF_VSQ    39155712u        // fp8 vsum x1024
#define OFF_H2T    39185152u
#define OFF_FC3P   39217920u        // 4,816,896 -> end 44,034,816 (176MB < 616MB)

typedef __attribute__((ext_vector_type(8))) short short8;
typedef __attribute__((ext_vector_type(4))) float f32x4;
typedef long long i64;

__device__ __forceinline__ unsigned short f2b(float f) {
  union { float f; unsigned u; } v; v.f = f;
  unsigned r = v.u + 0x7fffu + ((v.u >> 16) & 1u);
  return (unsigned short)(r >> 16);
}

__device__ __forceinline__ float b2f(unsigned short h) {
  union { unsigned u; float f; } v; v.u = ((unsigned)h) << 16;
  return v.f;
}

// float -> OCP e4m3fn (RNE, flush<2^-6, clamp) -- software fallback
__device__ __forceinline__ unsigned f2q_fast(float x) {
  union { float f; unsigned u; } v; v.f = x;
  unsigned s = (v.u >> 24) & 0x80u;
  unsigned au = v.u & 0x7fffffffu;
  if (au < 0x3c800000u) return s;
  if (au >= 0x43e00000u) return s | 0x7eu;
  unsigned r = au + 0x7ffffu + ((au >> 20) & 1u);
  unsigned e = (r >> 23) - 120u;
  unsigned m = (r >> 20) & 7u;
  return s | (e << 3) | m;
}

__device__ __forceinline__ unsigned fp8pair(float a, float b) {
#if __has_builtin(__builtin_amdgcn_cvt_pk_fp8_f32)
  return (unsigned)__builtin_amdgcn_cvt_pk_fp8_f32(a, b, 0, false) & 0xffffu;
#else
  return f2q_fast(a) | (f2q_fast(b) << 8);
#endif
}

__device__ __forceinline__ float rcpf(float x) {
#if __has_builtin(__builtin_amdgcn_rcpf)
  return __builtin_amdgcn_rcpf(x);
#else
  return 1.0f / x;
#endif
}

// ---------------- merged weight-pack kernel (R12 combined form) ----------------
// [0,256): conv1_w -> bf16 C1WB   [256,512): pc_w -> fp8 PCWQ
// [512,4643): W -> fp8 Wq2 + Wq (2 rows/thread, LDS transpose)
// [4643,4694): zero S
__global__ __launch_bounds__(256) void k_pack(const float* __restrict__ conv1_w,
                                              const float* __restrict__ pc_w,
                                              const float* __restrict__ W,
                                              unsigned short* __restrict__ C1WB,
                                              unsigned char* __restrict__ PCWQ,
                                              unsigned char* __restrict__ Wq2,
                                              unsigned char* __restrict__ Wq,
                                              float* __restrict__ S) {
  __shared__ unsigned char sq[64 * 128];
  int bb = blockIdx.x;
  int t = threadIdx.x;
  if (bb < 256) {
    if (t < 128) {
#pragma unroll
      for (int ci = 0; ci < 3; ++ci) {
        float v = (t < 121) ? conv1_w[bb * 363 + ci * 121 + t] : 0.f;
        C1WB[(ci * 256 + bb) * 128 + t] = f2b(v);
      }
    }
  } else if (bb < 512) {
    int co = bb - 256;
    for (int e = t; e < 20736; e += 256) {
      int ci = e / 81, tap = e - ci * 81;
      PCWQ[(size_t)ci * 26624 + co * 104 + tap] =
          (unsigned char)f2q_fast(pc_w[(size_t)co * 20736 + e] * 64.f);
    }
    for (int tap = 81; tap < 104; ++tap)
      PCWQ[(size_t)t * 26624 + co * 104 + tap] = 0;
  } else if (bb < 4643) {
    size_t base = (size_t)(bb - 512) * 8192;  // 64 rows of 128 floats
    int g = t >> 3, seg = t & 7;
    int r0 = 2 * g, r1 = 2 * g + 1;
    const f32x4* s0 = (const f32x4*)(W + base + r0 * 128 + seg * 16);
    const f32x4* s1 = (const f32x4*)(W + base + r1 * 128 + seg * 16);
    f32x4 a0 = s0[0], a1 = s0[1], a2 = s0[2], a3 = s0[3];
    f32x4 c0 = s1[0], c1 = s1[1], c2 = s1[2], c3 = s1[3];
    asm volatile("" :: "v"(a0), "v"(a1), "v"(a2), "v"(a3),
                       "v"(c0), "v"(c1), "v"(c2), "v"(c3));
    unsigned w0[4], w1[4];
    f32x4 va[4] = {a0, a1, a2, a3}, vc[4] = {c0, c1, c2, c3};
#pragma unroll
    for (int j = 0; j < 4; ++j) {
      w0[j] = fp8pair(va[j][0] * 64.f, va[j][1] * 64.f) |
              (fp8pair(va[j][2] * 64.f, va[j][3] * 64.f) << 16);
      w1[j] = fp8pair(vc[j][0] * 64.f, vc[j][1] * 64.f) |
              (fp8pair(vc[j][2] * 64.f, vc[j][3] * 64.f) << 16);
    }
    *(uint4*)(Wq2 + base + r0 * 128 + seg * 16) = make_uint4(w0[0], w0[1], w0[2], w0[3]);
    *(uint4*)(Wq2 + base + r1 * 128 + seg * 16) = make_uint4(w1[0], w1[1], w1[2], w1[3]);
#pragma unroll
    for (int e = 0; e < 16; ++e) {
      int idx = seg * 16 + e, d = idx >> 3, i = idx & 7;
      sq[r0 * 128 + i * 16 + d] = (unsigned char)((w0[e >> 2] >> ((e & 3) * 8)) & 0xffu);
      sq[r1 * 128 + i * 16 + d] = (unsigned char)((w1[e >> 2] >> ((e & 3) * 8)) & 0xffu);
    }
    __syncthreads();
    *(uint4*)(Wq + base + (size_t)t * 16) = ((const uint4*)sq)[t];
    *(uint4*)(Wq + base + 4096 + (size_t)t * 16) = ((const uint4*)sq)[256 + t];
  } else {
    int idx = (bb - 4643) * 1024 + t * 4;  // 51*1024 = 52224
    *(float4*)(S + idx) = make_float4(0.f, 0.f, 0.f, 0.f);
  }
}

// ---------------- conv1 via bf16 MFMA, co-split x2, bf16 feat2 output ----------------
__global__ __launch_bounds__(256) void k_c1m(const float* __restrict__ x,
                                             const unsigned short* __restrict__ C1WB,
                                             const float* __restrict__ bias,
                                             unsigned short* __restrict__ feat2) {
  __shared__ unsigned short sh[48 * 128 + 128 * 128];
  unsigned short* lA = sh;
  unsigned short* lB = sh + 48 * 128;
  unsigned short* obuf = sh + 48 * 128;  // reused in epilogue (4608 ush < lB)

  int bx = blockIdx.x;
  int hf = blockIdx.y;  // co half
  int b = bx / 34, ho = bx % 34;
  int t = threadIdx.x;
  int lane = t & 63, wv = t >> 6;
  int l15 = lane & 15, lh = lane >> 4;
  int rx = l15 & 7;

  {
    uint4 zz = make_uint4(0, 0, 0, 0);
    uint4* z = (uint4*)lA;
    for (int i = t; i < 48 * 128 / 8; i += 256) z[i] = zz;
  }
  __syncthreads();

  f32x4 acc[3][2];
#pragma unroll
  for (int mf = 0; mf < 3; ++mf)
#pragma unroll
    for (int nf = 0; nf < 2; ++nf) acc[mf][nf] = (f32x4){0.f, 0.f, 0.f, 0.f};

#pragma unroll 1
  for (int ci = 0; ci < 3; ++ci) {
    {
      const uint4* Bsrc = (const uint4*)(C1WB + ci * 32768 + hf * 16384);
#pragma unroll
      for (int i = 0; i < 8; ++i) {
        int f = i * 256 + t;
        int row = f >> 4, cu = f & 15;
        ((uint4*)lB)[row * 16 + (cu ^ (row & 7))] = Bsrc[f];
      }
    }
    for (int tk = t; tk < 374; tk += 256) {
      int kh = tk / 34, wo = tk - kh * 34;
      const float* src = x + ((size_t)(b * 3 + ci) * 112 + ho * 3 + kh) * 112 + wo * 3;
#pragma unroll
      for (int j = 0; j < 11; ++j) {
        int tap = kh * 11 + j;
        int cu = tap >> 3;
        lA[wo * 128 + (((cu ^ (wo & 7)) << 3) | (tap & 7))] = f2b(src[j]);
      }
    }
    __syncthreads();

#pragma unroll
    for (int s = 0; s < 4; ++s) {
      int cub = ((s * 4 + lh) ^ rx) << 3;
      short8 a0 = *(const short8*)(lA + (0 + l15) * 128 + cub);
      short8 a1 = *(const short8*)(lA + (16 + l15) * 128 + cub);
      short8 a2 = *(const short8*)(lA + (32 + l15) * 128 + cub);
      short8 b0 = *(const short8*)(lB + (wv * 32 + 0 + l15) * 128 + cub);
      short8 b1 = *(const short8*)(lB + (wv * 32 + 16 + l15) * 128 + cub);
      acc[0][0] = __builtin_amdgcn_mfma_f32_16x16x32_bf16(a0, b0, acc[0][0], 0, 0, 0);
      acc[0][1] = __builtin_amdgcn_mfma_f32_16x16x32_bf16(a0, b1, acc[0][1], 0, 0, 0);
      acc[1][0] = __builtin_amdgcn_mfma_f32_16x16x32_bf16(a1, b0, acc[1][0], 0, 0, 0);
      acc[1][1] = __builtin_amdgcn_mfma_f32_16x16x32_bf16(a1, b1, acc[1][1], 0, 0, 0);
      acc[2][0] = __builtin_amdgcn_mfma_f32_16x16x32_bf16(a2, b0, acc[2][0], 0, 0, 0);
      acc[2][1] = __builtin_amdgcn_mfma_f32_16x16x32_bf16(a2, b1, acc[2][1], 0, 0, 0);
    }
    __syncthreads();
  }

  float bv[2];
#pragma unroll
  for (int nf = 0; nf < 2; ++nf) bv[nf] = bias[hf * 128 + wv * 32 + nf * 16 + l15];
#pragma unroll
  for (int mf = 0; mf < 3; ++mf)
#pragma unroll
    for (int nf = 0; nf < 2; ++nf)
#pragma unroll
      for (int r = 0; r < 4; ++r) {
        int wo = mf * 16 + lh * 4 + r;
        if (wo < 36)
          obuf[(wv * 32 + nf * 16 + l15) * 36 + wo] =
              f2b(fmaxf(acc[mf][nf][r] + bv[nf], 0.f));
      }
  __syncthreads();
  // 128 co x 36 bf16 = 4608 ushorts = 576 uint4, contiguous
  uint4* dst = (uint4*)(feat2 + (size_t)bx * 9216 + hf * 4608);
  const uint4* srcb = (const uint4*)obuf;
  for (int i = t; i < 576; i += 256) dst[i] = srcb[i];
}

// ---------------- pc conv gather (bf16 feat2 -> fp8) ----------------
__device__ __forceinline__ void pc_gather8(const unsigned short* __restrict__ feat2,
                                           unsigned char* __restrict__ dstbuf,
                                           int mb, int ci, int t) {
  for (int task = t; task < 576; task += 256) {
    int m = task / 9, kh = task - m * 9;
    int gm = mb * 64 + m;
    if (gm < 2592) {
      int b = gm / 81, p = gm - b * 81;
      int ho = p / 9, wo = p - ho * 9;
      const unsigned short* src =
          feat2 + ((size_t)(b * 34 + ho * 3 + kh) * 256 + ci) * 36 + wo * 3;
      unsigned char* dst = dstbuf + m * 104 + kh * 9;
      unsigned p01 = fp8pair(b2f(src[0]), b2f(src[1]));
      unsigned p23 = fp8pair(b2f(src[2]), b2f(src[3]));
      unsigned p45 = fp8pair(b2f(src[4]), b2f(src[5]));
      unsigned p67 = fp8pair(b2f(src[6]), b2f(src[7]));
      unsigned p8  = fp8pair(b2f(src[8]), 0.f);
      dst[0] = p01; dst[1] = p01 >> 8;
      dst[2] = p23; dst[3] = p23 >> 8;
      dst[4] = p45; dst[5] = p45 >> 8;
      dst[6] = p67; dst[7] = p67 >> 8;
      dst[8] = p8;
    }
  }
}

// ---------------- primary caps conv: fp8 MFMA, kc=16, fp16 partials ----------------
__global__ __launch_bounds__(256, 3) void k_pc4(const unsigned short* __restrict__ feat2,
                                                const unsigned char* __restrict__ PCWQ,
                                                __half* __restrict__ pcp) {
  __shared__ unsigned char lA[2][64 * 104];

  int mb = blockIdx.x, kc = blockIdx.y;  // (41, 16)
  int t = threadIdx.x;
  int lane = t & 63, wv = t >> 6;
  int l15 = lane & 15, lh = lane >> 4;

  {
    uint4 zz = make_uint4(0, 0, 0, 0);
    uint4* z = (uint4*)lA;
    for (int i = t; i < 2 * 64 * 104 / 16; i += 256) z[i] = zz;
  }
  __syncthreads();
  pc_gather8(feat2, lA[0], mb, kc * 16, t);
  __syncthreads();

  f32x4 acc[4][4];
#pragma unroll
  for (int mf = 0; mf < 4; ++mf)
#pragma unroll
    for (int nf = 0; nf < 4; ++nf) acc[mf][nf] = (f32x4){0.f, 0.f, 0.f, 0.f};

#pragma unroll 1
  for (int cil = 0; cil < 16; ++cil) {
    int ci = kc * 16 + cil;
    int cur = cil & 1;

    i64 bfr[4][3];
    const unsigned char* Bbase = PCWQ + (size_t)ci * 26624 + (wv * 64 + l15) * 104 + lh * 8;
#pragma unroll
    for (int nf = 0; nf < 4; ++nf)
#pragma unroll
      for (int s = 0; s < 3; ++s)
        bfr[nf][s] = *(const i64*)(Bbase + nf * 16 * 104 + s * 32);

    if (cil < 15) pc_gather8(feat2, lA[cur ^ 1], mb, ci + 1, t);

    const unsigned char* arow = lA[cur] + l15 * 104 + lh * 8;
#pragma unroll
    for (int s = 0; s < 3; ++s) {
      i64 a0 = *(const i64*)(arow + s * 32);
      i64 a1 = *(const i64*)(arow + 16 * 104 + s * 32);
      i64 a2 = *(const i64*)(arow + 32 * 104 + s * 32);
      i64 a3 = *(const i64*)(arow + 48 * 104 + s * 32);
      acc[0][0] = __builtin_amdgcn_mfma_f32_16x16x32_fp8_fp8(a0, bfr[0][s], acc[0][0], 0, 0, 0);
      acc[0][1] = __builtin_amdgcn_mfma_f32_16x16x32_fp8_fp8(a0, bfr[1][s], acc[0][1], 0, 0, 0);
      acc[0][2] = __builtin_amdgcn_mfma_f32_16x16x32_fp8_fp8(a0, bfr[2][s], acc[0][2], 0, 0, 0);
      acc[0][3] = __builtin_amdgcn_mfma_f32_16x16x32_fp8_fp8(a0, bfr[3][s], acc[0][3], 0, 0, 0);
      acc[1][0] = __builtin_amdgcn_mfma_f32_16x16x32_fp8_fp8(a1, bfr[0][s], acc[1][0], 0, 0, 0);
      acc[1][1] = __builtin_amdgcn_mfma_f32_16x16x32_fp8_fp8(a1, bfr[1][s], acc[1][1], 0, 0, 0);
      acc[1][2] = __builtin_amdgcn_mfma_f32_16x16x32_fp8_fp8(a1, bfr[2][s], acc[1][2], 0, 0, 0);
      acc[1][3] = __builtin_amdgcn_mfma_f32_16x16x32_fp8_fp8(a1, bfr[3][s], acc[1][3], 0, 0, 0);
      acc[2][0] = __builtin_amdgcn_mfma_f32_16x16x32_fp8_fp8(a2, bfr[0][s], acc[2][0], 0, 0, 0);
      acc[2][1] = __builtin_amdgcn_mfma_f32_16x16x32_fp8_fp8(a2, bfr[1][s], acc[2][1], 0, 0, 0);
      acc[2][2] = __builtin_amdgcn_mfma_f32_16x16x32_fp8_fp8(a2, bfr[2][s], acc[2][2], 0, 0, 0);
      acc[2][3] = __builtin_amdgcn_mfma_f32_16x16x32_fp8_fp8(a2, bfr[3][s], acc[2][3], 0, 0, 0);
      acc[3][0] = __builtin_amdgcn_mfma_f32_16x16x32_fp8_fp8(a3, bfr[0][s], acc[3][0], 0, 0, 0);
      acc[3][1] = __builtin_amdgcn_mfma_f32_16x16x32_fp8_fp8(a3, bfr[1][s], acc[3][1], 0, 0, 0);
      acc[3][2] = __builtin_amdgcn_mfma_f32_16x16x32_fp8_fp8(a3, bfr[2][s], acc[3][2], 0, 0, 0);
      acc[3][3] = __builtin_amdgcn_mfma_f32_16x16x32_fp8_fp8(a3, bfr[3][s], acc[3][3], 0, 0, 0);
    }
    __syncthreads();
  }

#pragma unroll
  for (int mf = 0; mf < 4; ++mf) {
    int gm = mb * 64 + mf * 16 + lh * 4;
    if (gm < 2592) {
      __half* dst = pcp + (size_t)kc * 663552 + (size_t)gm * 256 + wv * 64 + l15;
#pragma unroll
      for (int nf = 0; nf < 4; ++nf)
#pragma unroll
        for (int r = 0; r < 4; ++r)
          dst[(size_t)r * 256 + nf * 16] = __float2half(acc[mf][nf][r]);
    }
  }
}

// ---------------- fused transpose-reduce-squash: pcp(16 fp16 slices) -> u2 ----------------
__global__ __launch_bounds__(256) void k_rs(const __half* __restrict__ pcp,
                                            const float* __restrict__ pcb,
                                            float* __restrict__ u2) {
  __shared__ float tile[81 * 17];
  int b = blockIdx.x;    // 32
  int cog = blockIdx.y;  // 16
  int c0 = cog * 16;
  int t = threadIdx.x;

  for (int e = t; e < 1296; e += 256) {
    int p = e >> 4, col = e & 15;
    const __half* base = pcp + (size_t)(b * 81 + p) * 256 + c0 + col;
    float s = 0.f;
#pragma unroll
    for (int c = 0; c < 16; ++c) s += __half2float(base[(size_t)c * 663552]);
    tile[p * 17 + col] = pcb[c0 + col] + s * 0.015625f;  // /64 (W x64)
  }
  __syncthreads();

  if (t < 162) {
    float v[8];
    float sq = 0.f;
#pragma unroll
    for (int i = 0; i < 8; ++i) {
      int g = t * 8 + i;
      int col = g / 81, p = g - col * 81;
      v[i] = tile[p * 17 + col];
      sq += v[i] * v[i];
    }
    float sc = (sq / (1.f + sq)) / sqrtf(sq + 1e-8f);
    int n = cog * 162 + t;
    float4* dst = (float4*)(u2 + ((size_t)b * 2592 + n) * 8);
    dst[0] = make_float4(v[0] * sc, v[1] * sc, v[2] * sc, v[3] * sc);
    dst[1] = make_float4(v[4] * sc, v[5] * sc, v[6] * sc, v[7] * sc);
  }
}

// ---------------- routing kernel A3 (fp8 MFMA, o-split x3): E + partial den ----------------
__global__ __launch_bounds__(128) void k_A3(const unsigned char* __restrict__ Wq,
                                            const float* __restrict__ u2,
                                            const unsigned char* __restrict__ vq,
                                            __half* __restrict__ cT,
                                            float* __restrict__ den) {
  int nb = blockIdx.x;   // 648
  int ch = blockIdx.y;   // 3
  int o0 = ch * 34;
  int t = threadIdx.x, wv = t >> 6, lane = t & 63;
  int l15 = lane & 15, g = lane >> 4;
  int n0 = nb * 4 + 2 * wv;
  int nl = g >> 1, ih = (g & 1) * 4;

  float4 u0 = *(const float4*)(u2 + (((size_t)l15 * 2592 + n0 + nl) * 8 + ih));
  float4 u1 = *(const float4*)(u2 + (((size_t)(l15 + 16) * 2592 + n0 + nl) * 8 + ih));

  int nlA = l15 >> 3, iA = l15 & 7;
  const unsigned char* Ap = Wq + (((size_t)(n0 + nlA)) * 8 + iA) * 16 + (g & 1) * 8 +
                            (size_t)o0 * 331776;
  const unsigned char* B0p = vq + (size_t)l15 * 16 + (g & 1) * 8 + (size_t)o0 * 512;
  bool act = (g < 2);

  float den0 = 0.f, den1 = 0.f;
#pragma unroll 2
  for (int oo = 0; oo < 34; ++oo) {
    i64 a = 0, b0 = 0, b1 = 0;
    if (act) {
      a  = *(const i64*)(Ap + (size_t)oo * 331776);
      b0 = *(const i64*)(B0p + (size_t)oo * 512);
      b1 = *(const i64*)(B0p + (size_t)oo * 512 + 256);
    }
    f32x4 d0 = {0.f, 0.f, 0.f, 0.f}, d1 = {0.f, 0.f, 0.f, 0.f};
    d0 = __builtin_amdgcn_mfma_f32_16x16x32_fp8_fp8(a, b0, d0, 0, 0, 0);
    d1 = __builtin_amdgcn_mfma_f32_16x16x32_fp8_fp8(a, b1, d1, 0, 0, 0);
    float p0 = d0[0] * u0.x + d0[1] * u0.y + d0[2] * u0.z + d0[3] * u0.w;
    float p1 = d1[0] * u1.x + d1[1] * u1.y + d1[2] * u1.z + d1[3] * u1.w;
    p0 += __shfl_xor(p0, 16);
    p1 += __shfl_xor(p1, 16);
    p0 *= 1.52587890625e-05f;  // / (64 * 1024)
    p1 *= 1.52587890625e-05f;
    float e0 = __expf(p0), e1 = __expf(p1);
    den0 += e0; den1 += e1;
    if ((g & 1) == 0) {
      __half* dst = cT + ((size_t)(o0 + oo) * 2592 + n0 + nl) * 32 + l15;
      dst[0]  = __float2half(e0);
      dst[16] = __float2half(e1);
    }
  }
  if ((g & 1) == 0) {
    atomicAdd(den + (n0 + nl) * 32 + l15, den0);
    atomicAdd(den + (n0 + nl) * 32 + l15 + 16, den1);
  }
}

// ---------------- routing kernel B (fp8 MFMA): s = sum (E/den)*xhat ----------------
__device__ __forceinline__ i64 cu_pack8(float c, float4 a, float4 b) {
  union { unsigned u[2]; i64 v; } r;
  r.u[0] = fp8pair(c * a.x, c * a.y) | (fp8pair(c * a.z, c * a.w) << 16);
  r.u[1] = fp8pair(c * b.x, c * b.y) | (fp8pair(c * b.z, c * b.w) << 16);
  return r.v;
}

template <bool HASC>
__global__ __launch_bounds__(256) void k_B3(const unsigned char* __restrict__ Wq2,
                                            const float* __restrict__ u2,
                                            const __half* __restrict__ cT,
                                            const float* __restrict__ den,
                                            float* __restrict__ s) {
  int o = blockIdx.x, kc = blockIdx.y;  // (102, 12)
  int t = threadIdx.x, lane = t & 63, wv = t >> 6;
  int l15 = lane & 15, h = lane >> 4;

  f32x4 acc0 = {0.f, 0.f, 0.f, 0.f}, acc1 = {0.f, 0.f, 0.f, 0.f};

#pragma unroll 1
  for (int st = wv; st < 54; st += 4) {
    int n = kc * 216 + st * 4 + h;
    i64 aq = *(const i64*)(Wq2 + (((size_t)o * 2592 + n) * 16 + l15) * 8);

    const float4* u0p = (const float4*)(u2 + ((size_t)l15 * 2592 + n) * 8);
    float4 u0a = u0p[0], u0b = u0p[1];
    const float4* u1p = (const float4*)(u2 + ((size_t)(l15 + 16) * 2592 + n) * 8);
    float4 u1a = u1p[0], u1b = u1p[1];

    float c0 = 16.0f, c1 = 16.0f;
    if (HASC) {
      const __half* cp = cT + ((size_t)o * 2592 + n) * 32;
      float i0 = rcpf(den[n * 32 + l15]);
      float i1 = rcpf(den[n * 32 + l15 + 16]);
      c0 = 16.0f * __half2float(cp[l15]) * i0;
      c1 = 16.0f * __half2float(cp[l15 + 16]) * i1;
    }
    i64 b0 = cu_pack8(c0, u0a, u0b);
    i64 b1 = cu_pack8(c1, u1a, u1b);

    acc0 = __builtin_amdgcn_mfma_f32_16x16x32_fp8_fp8(aq, b0, acc0, 0, 0, 0);
    acc1 = __builtin_amdgcn_mfma_f32_16x16x32_fp8_fp8(aq, b1, acc1, 0, 0, 0);
  }

#pragma unroll
  for (int r = 0; r < 4; ++r) {
    atomicAdd(s + ((size_t)l15 * 102 + o) * 16 + h * 4 + r, acc0[r]);
    atomicAdd(s + ((size_t)(l15 + 16) * 102 + o) * 16 + h * 4 + r, acc1[r]);
  }
}

// ---------------- squash v; optional fp8 vsum; optional S re-zero + den zero ----------------
__global__ void k_R(const float* __restrict__ s, float scale,
                    float* __restrict__ vout, const float* __restrict__ addin,
                    unsigned char* __restrict__ vsq, float* __restrict__ szero,
                    float* __restrict__ dzero) {
  int t = blockIdx.x * 256 + threadIdx.x;  // grid 13*256 = 3328
  if (dzero) {
    for (int i = t; i < 82944; i += 3328) dzero[i] = 0.f;
  }
  if (t >= 3264) return;
  const float* sp = s + t * 16;
  float r[16];
  float sq = 0.f;
#pragma unroll
  for (int d = 0; d < 16; ++d) {
    r[d] = sp[d] * scale;
    sq += r[d] * r[d];
  }
  if (szero) {
#pragma unroll
    for (int d = 0; d < 16; ++d) szero[t * 16 + d] = 0.f;
  }
  float sc = (sq / (1.f + sq)) / sqrtf(sq + 1e-8f);
  float vv[16];
#pragma unroll
  for (int d = 0; d < 16; ++d) {
    vv[d] = r[d] * sc;
    vout[t * 16 + d] = vv[d];
  }
  if (vsq) {
    int b = t / 102, o = t - b * 102;
    float w[16];
#pragma unroll
    for (int d = 0; d < 16; ++d)
      w[d] = (addin ? (addin[t * 16 + d] + vv[d]) : vv[d]) * 1024.f;
    unsigned words[4];
#pragma unroll
    for (int q = 0; q < 4; ++q)
      words[q] = fp8pair(w[4 * q], w[4 * q + 1]) | (fp8pair(w[4 * q + 2], w[4 * q + 3]) << 16);
    *(uint4*)(vsq + ((size_t)o * 32 + b) * 16) =
        make_uint4(words[0], words[1], words[2], words[3]);
  }
}

// ---------------- fused fc1+fc2: block = bq (4 batch items), h1 in LDS ----------------
__global__ __launch_bounds__(512) void k_fc12(const float* __restrict__ v2,
                                              const int* __restrict__ tgt,
                                              const float* __restrict__ w1,
                                              const float* __restrict__ b1,
                                              const float* __restrict__ w2,
                                              const float* __restrict__ b2,
                                              float* __restrict__ h2T) {
  __shared__ float h1s[4][512];
  int bq = blockIdx.x;  // 8
  int t = threadIdx.x;  // 512
#pragma unroll
  for (int bi = 0; bi < 4; ++bi) {
    int b = bq * 4 + bi;
    int tb = tgt[b];
    float acc = b1[t];
    const float* vv = v2 + (b * 102 + tb) * 16;
    const float* wr = w1 + (tb * 16) * 512 + t;
#pragma unroll
    for (int d = 0; d < 16; ++d) acc += vv[d] * wr[d * 512];
    h1s[bi][t] = fmaxf(acc, 0.f);
  }
  __syncthreads();
  float a0[4], a1[4];
#pragma unroll
  for (int bi = 0; bi < 4; ++bi) { a0[bi] = b2[t]; a1[bi] = b2[t + 512]; }
  for (int k = 0; k < 512; ++k) {
    float w0 = w2[k * 1024 + t], w1v = w2[k * 1024 + t + 512];
#pragma unroll
    for (int bi = 0; bi < 4; ++bi) {
      float h = h1s[bi][k];
      a0[bi] += h * w0;
      a1[bi] += h * w1v;
    }
  }
  float4 o0, o1;
  o0.x = fmaxf(a0[0], 0.f); o0.y = fmaxf(a0[1], 0.f);
  o0.z = fmaxf(a0[2], 0.f); o0.w = fmaxf(a0[3], 0.f);
  o1.x = fmaxf(a1[0], 0.f); o1.y = fmaxf(a1[1], 0.f);
  o1.z = fmaxf(a1[2], 0.f); o1.w = fmaxf(a1[3], 0.f);
  *(float4*)(h2T + t * 32 + bq * 4) = o0;
  *(float4*)(h2T + (t + 512) * 32 + bq * 4) = o1;
}

__global__ void k_fc3a(const float* __restrict__ h2T, const float* __restrict__ w3,
                       float* __restrict__ p) {
  int j = blockIdx.x * 128 + threadIdx.x;
  int ky = blockIdx.y;
  float acc[32];
#pragma unroll
  for (int i = 0; i < 32; ++i) acc[i] = 0.f;
  int k0 = ky * 256;
  for (int k = k0; k < k0 + 256; ++k) {
    float wv = w3[(size_t)k * 37632 + j];
    const float4* hp = (const float4*)(h2T + k * 32);
#pragma unroll
    for (int q = 0; q < 8; ++q) {
      float4 h = hp[q];
      acc[q * 4 + 0] += h.x * wv; acc[q * 4 + 1] += h.y * wv;
      acc[q * 4 + 2] += h.z * wv; acc[q * 4 + 3] += h.w * wv;
    }
  }
#pragma unroll
  for (int i = 0; i < 32; ++i)
    p[((size_t)ky * 32 + i) * 37632 + j] = acc[i];
}

__global__ void k_fc3b(const float* __restrict__ p, const float* __restrict__ b3,
                       float* __restrict__ out) {
  int j = blockIdx.x * 256 + threadIdx.x;
  float bv = b3[j];
#pragma unroll 1
  for (int b = 0; b < 32; ++b) {
    float s = bv + p[(size_t)b * 37632 + j] + p[(size_t)(32 + b) * 37632 + j] +
              p[(size_t)(64 + b) * 37632 + j] + p[(size_t)(96 + b) * 37632 + j];
    out[52224 + (size_t)b * 37632 + j] = 1.0f / (1.0f + __expf(-s));
  }
}

// ---------------- host ----------------
extern "C" void kernel_launch(void* const* d_in, const int* in_sizes, int n_in,
                              void* d_out, int out_size, void* d_ws, size_t ws_size,
                              hipStream_t stream) {
  const float* x       = (const float*)d_in[0];
  const int*   targets = (const int*)d_in[1];
  const float* conv1_w = (const float*)d_in[2];
  const float* conv1_b = (const float*)d_in[3];
  const float* pc_w    = (const float*)d_in[4];
  const float* pc_b    = (const float*)d_in[5];
  const float* W       = (const float*)d_in[6];
  const float* fc1_w   = (const float*)d_in[7];
  const float* fc1_b   = (const float*)d_in[8];
  const float* fc2_w   = (const float*)d_in[9];
  const float* fc2_b   = (const float*)d_in[10];
  const float* fc3_w   = (const float*)d_in[11];
  const float* fc3_b   = (const float*)d_in[12];
  float* out = (float*)d_out;
  float* ws = (float*)d_ws;

  unsigned short* FEAT2 = (unsigned short*)(ws + OFF_FEAT);
  unsigned short* C1WB = (unsigned short*)(ws + OFF_C1WT);
  unsigned char* PCWQ = (unsigned char*)(ws + OFF_PCWQ);
  __half* PCP = (__half*)(ws + OFF_PCP);
  unsigned char* WQ2 = (unsigned char*)(ws + OFF_WQ2);
  unsigned char* WQ  = (unsigned char*)(ws + OFF_WQ);
  float* U2   = ws + OFF_U2;
  __half* CT  = (__half*)(ws + OFF_CT);
  float* DEN  = ws + OFF_DEN;
  float* S    = ws + OFF_S;
  float* V0   = ws + OFF_V0;
  float* V1   = ws + OFF_V1;
  unsigned char* VSQ = (unsigned char*)(ws + OFF_VSQ);
  float* H2T  = ws + OFF_H2T;
  float* FC3P = ws + OFF_FC3P;

  // all weight packs + initial S zero in one launch (R12 combined form)
  k_pack<<<dim3(4694), 256, 0, stream>>>(conv1_w, pc_w, W, C1WB, PCWQ, WQ2, WQ, S);

  // conv1 + relu (bf16 MFMA, co-split, bf16 feat2)
  k_c1m<<<dim3(1088, 2), 256, 0, stream>>>(x, C1WB, conv1_b, FEAT2);

  // primary caps conv + fused reduce/squash
  k_pc4<<<dim3(41, 16), 256, 0, stream>>>(FEAT2, PCWQ, PCP);
  k_rs<<<dim3(32, 16), 256, 0, stream>>>(PCP, pc_b, U2);

  // ---- routing ---- (scales: W x64, cu x16 -> /1024; vq x1024 -> logits /65536)
  k_B3<false><<<dim3(102, 12), 256, 0, stream>>>(WQ2, U2, nullptr, nullptr, S);
  k_R<<<dim3(13), 256, 0, stream>>>(S, 1.0f / (102.0f * 1024.0f), V0, nullptr, VSQ, S, DEN);

  k_A3<<<dim3(648, 3), 128, 0, stream>>>(WQ, U2, VSQ, CT, DEN);
  k_B3<true><<<dim3(102, 12), 256, 0, stream>>>(WQ2, U2, CT, DEN, S);
  k_R<<<dim3(13), 256, 0, stream>>>(S, 1.0f / 1024.0f, V1, V0, VSQ, S, DEN);  // vsq = v0+v1

  k_A3<<<dim3(648, 3), 128, 0, stream>>>(WQ, U2, VSQ, CT, DEN);
  k_B3<true><<<dim3(102, 12), 256, 0, stream>>>(WQ2, U2, CT, DEN, S);
  k_R<<<dim3(13), 256, 0, stream>>>(S, 1.0f / 1024.0f, out, nullptr, nullptr, nullptr, nullptr);

  // ---- reconstruction ----
  k_fc12<<<dim3(8), 512, 0, stream>>>(out, targets, fc1_w, fc1_b, fc2_w, fc2_b, H2T);
  k_fc3a<<<dim3(294, 4), 128, 0, stream>>>(H2T, fc3_w, FC3P);
  k_fc3b<<<dim3(147), 256, 0, stream>>>(FC3P, fc3_b, out);
}

// Round 16
// 542.722 us; speedup vs baseline: 1.0221x; 1.0119x over previous
//
#include <hip/hip_runtime.h>
#include <hip/hip_fp16.h>
#include <math.h>

// ---------------- sizes ----------------
#define B32   32
#define OCLS  102
#define NCAPS 2592

// ---------------- ws map (floats) -- ws is 616 MB; flat, no overlays ----
#define OFF_FEAT   0u               // feat2[b][h][co][w36] bf16
#define OFF_C1WT   10027008u        // bf16 conv1 pack
#define OFF_PCWQ   10076160u        // fp8 pc pack
#define OFF_PCP    11780096u        // fp16 partials 16 slices
#define OFF_WQ2    17088512u        // fp8 W pack [o][n][d][i]
#define OFF_WQ     25555456u        // fp8 W pack [o][n][i][d]
#define OFF_U2     34022400u
#define OFF_CT     34685952u        // fp16 E[o][n][b]
#define OFF_DEN    38916096u        // f32 den[n][b]
#define OFF_S      38999040u
#define OFF_V0     39051264u
#define OFF_V1     39103488u
#define OFF_VSQ    39155712u        // fp8 vsum x1024
#define OFF_H2T    39185152u
#define OFF_FC3P   39217920u        // -> end 44,034,816 (176MB < 616MB)

typedef __attribute__((ext_vector_type(8))) short short8;
typedef __attribute__((ext_vector_type(4))) float f32x4;
typedef long long i64;

__device__ __forceinline__ unsigned short f2b(float f) {
  union { float f; unsigned u; } v; v.f = f;
  unsigned r = v.u + 0x7fffu + ((v.u >> 16) & 1u);
  return (unsigned short)(r >> 16);
}

__device__ __forceinline__ float b2f(unsigned short h) {
  union { unsigned u; float f; } v; v.u = ((unsigned)h) << 16;
  return v.f;
}

// float -> OCP e4m3fn (RNE, flush<2^-6, clamp) -- software fallback
__device__ __forceinline__ unsigned f2q_fast(float x) {
  union { float f; unsigned u; } v; v.f = x;
  unsigned s = (v.u >> 24) & 0x80u;
  unsigned au = v.u & 0x7fffffffu;
  if (au < 0x3c800000u) return s;
  if (au >= 0x43e00000u) return s | 0x7eu;
  unsigned r = au + 0x7ffffu + ((au >> 20) & 1u);
  unsigned e = (r >> 23) - 120u;
  unsigned m = (r >> 20) & 7u;
  return s | (e << 3) | m;
}

__device__ __forceinline__ unsigned fp8pair(float a, float b) {
#if __has_builtin(__builtin_amdgcn_cvt_pk_fp8_f32)
  return (unsigned)__builtin_amdgcn_cvt_pk_fp8_f32(a, b, 0, false) & 0xffffu;
#else
  return f2q_fast(a) | (f2q_fast(b) << 8);
#endif
}

__device__ __forceinline__ float rcpf(float x) {
#if __has_builtin(__builtin_amdgcn_rcpf)
  return __builtin_amdgcn_rcpf(x);
#else
  return 1.0f / x;
#endif
}

// ---------------- k_pack0: conv1_w -> bf16 C1WB (must precede k_c1m) ----------------
__global__ __launch_bounds__(128) void k_pack0(const float* __restrict__ conv1_w,
                                               unsigned short* __restrict__ C1WB) {
  int co = blockIdx.x;
  int t = threadIdx.x;
#pragma unroll
  for (int ci = 0; ci < 3; ++ci) {
    float v = (t < 121) ? conv1_w[co * 363 + ci * 121 + t] : 0.f;
    C1WB[(ci * 256 + co) * 128 + t] = f2b(v);
  }
}

// ---------------- conv1 (bf16 MFMA, co-split) ++ horizontal-fused pc_w pack ----------
// grid 2432: [0,2176) conv blocks (bx=bb>>1, hf=bb&1); [2176,2432) pc_w->fp8 PCWQ.
__global__ __launch_bounds__(256) void k_c1m(const float* __restrict__ x,
                                             const unsigned short* __restrict__ C1WB,
                                             const float* __restrict__ bias,
                                             unsigned short* __restrict__ feat2,
                                             const float* __restrict__ pc_w,
                                             unsigned char* __restrict__ PCWQ) {
  __shared__ unsigned short sh[48 * 128 + 128 * 128];
  int bb = blockIdx.x;
  int t = threadIdx.x;

  if (bb >= 2176) {  // pc_w pack branch (consumed by next kernel)
    int co = bb - 2176;
    for (int e = t; e < 20736; e += 256) {
      int ci = e / 81, tap = e - ci * 81;
      PCWQ[(size_t)ci * 26624 + co * 104 + tap] =
          (unsigned char)f2q_fast(pc_w[(size_t)co * 20736 + e] * 64.f);
    }
    for (int tap = 81; tap < 104; ++tap)
      PCWQ[(size_t)t * 26624 + co * 104 + tap] = 0;
    return;
  }

  unsigned short* lA = sh;
  unsigned short* lB = sh + 48 * 128;
  unsigned short* obuf = sh + 48 * 128;

  int bx = bb >> 1;
  int hf = bb & 1;
  int b = bx / 34, ho = bx % 34;
  int lane = t & 63, wv = t >> 6;
  int l15 = lane & 15, lh = lane >> 4;
  int rx = l15 & 7;

  {
    uint4 zz = make_uint4(0, 0, 0, 0);
    uint4* z = (uint4*)lA;
    for (int i = t; i < 48 * 128 / 8; i += 256) z[i] = zz;
  }
  __syncthreads();

  f32x4 acc[3][2];
#pragma unroll
  for (int mf = 0; mf < 3; ++mf)
#pragma unroll
    for (int nf = 0; nf < 2; ++nf) acc[mf][nf] = (f32x4){0.f, 0.f, 0.f, 0.f};

#pragma unroll 1
  for (int ci = 0; ci < 3; ++ci) {
    {
      const uint4* Bsrc = (const uint4*)(C1WB + ci * 32768 + hf * 16384);
#pragma unroll
      for (int i = 0; i < 8; ++i) {
        int f = i * 256 + t;
        int row = f >> 4, cu = f & 15;
        ((uint4*)lB)[row * 16 + (cu ^ (row & 7))] = Bsrc[f];
      }
    }
    for (int tk = t; tk < 374; tk += 256) {
      int kh = tk / 34, wo = tk - kh * 34;
      const float* src = x + ((size_t)(b * 3 + ci) * 112 + ho * 3 + kh) * 112 + wo * 3;
#pragma unroll
      for (int j = 0; j < 11; ++j) {
        int tap = kh * 11 + j;
        int cu = tap >> 3;
        lA[wo * 128 + (((cu ^ (wo & 7)) << 3) | (tap & 7))] = f2b(src[j]);
      }
    }
    __syncthreads();

#pragma unroll
    for (int s = 0; s < 4; ++s) {
      int cub = ((s * 4 + lh) ^ rx) << 3;
      short8 a0 = *(const short8*)(lA + (0 + l15) * 128 + cub);
      short8 a1 = *(const short8*)(lA + (16 + l15) * 128 + cub);
      short8 a2 = *(const short8*)(lA + (32 + l15) * 128 + cub);
      short8 b0 = *(const short8*)(lB + (wv * 32 + 0 + l15) * 128 + cub);
      short8 b1 = *(const short8*)(lB + (wv * 32 + 16 + l15) * 128 + cub);
      acc[0][0] = __builtin_amdgcn_mfma_f32_16x16x32_bf16(a0, b0, acc[0][0], 0, 0, 0);
      acc[0][1] = __builtin_amdgcn_mfma_f32_16x16x32_bf16(a0, b1, acc[0][1], 0, 0, 0);
      acc[1][0] = __builtin_amdgcn_mfma_f32_16x16x32_bf16(a1, b0, acc[1][0], 0, 0, 0);
      acc[1][1] = __builtin_amdgcn_mfma_f32_16x16x32_bf16(a1, b1, acc[1][1], 0, 0, 0);
      acc[2][0] = __builtin_amdgcn_mfma_f32_16x16x32_bf16(a2, b0, acc[2][0], 0, 0, 0);
      acc[2][1] = __builtin_amdgcn_mfma_f32_16x16x32_bf16(a2, b1, acc[2][1], 0, 0, 0);
    }
    __syncthreads();
  }

  float bv[2];
#pragma unroll
  for (int nf = 0; nf < 2; ++nf) bv[nf] = bias[hf * 128 + wv * 32 + nf * 16 + l15];
#pragma unroll
  for (int mf = 0; mf < 3; ++mf)
#pragma unroll
    for (int nf = 0; nf < 2; ++nf)
#pragma unroll
      for (int r = 0; r < 4; ++r) {
        int wo = mf * 16 + lh * 4 + r;
        if (wo < 36)
          obuf[(wv * 32 + nf * 16 + l15) * 36 + wo] =
              f2b(fmaxf(acc[mf][nf][r] + bv[nf], 0.f));
      }
  __syncthreads();
  uint4* dst = (uint4*)(feat2 + (size_t)bx * 9216 + hf * 4608);
  const uint4* srcb = (const uint4*)obuf;
  for (int i = t; i < 576; i += 256) dst[i] = srcb[i];
}

// ---------------- pc conv gather (bf16 feat2 -> fp8) ----------------
__device__ __forceinline__ void pc_gather8(const unsigned short* __restrict__ feat2,
                                           unsigned char* __restrict__ dstbuf,
                                           int mb, int ci, int t) {
  for (int task = t; task < 576; task += 256) {
    int m = task / 9, kh = task - m * 9;
    int gm = mb * 64 + m;
    if (gm < 2592) {
      int b = gm / 81, p = gm - b * 81;
      int ho = p / 9, wo = p - ho * 9;
      const unsigned short* src =
          feat2 + ((size_t)(b * 34 + ho * 3 + kh) * 256 + ci) * 36 + wo * 3;
      unsigned char* dst = dstbuf + m * 104 + kh * 9;
      unsigned p01 = fp8pair(b2f(src[0]), b2f(src[1]));
      unsigned p23 = fp8pair(b2f(src[2]), b2f(src[3]));
      unsigned p45 = fp8pair(b2f(src[4]), b2f(src[5]));
      unsigned p67 = fp8pair(b2f(src[6]), b2f(src[7]));
      unsigned p8  = fp8pair(b2f(src[8]), 0.f);
      dst[0] = p01; dst[1] = p01 >> 8;
      dst[2] = p23; dst[3] = p23 >> 8;
      dst[4] = p45; dst[5] = p45 >> 8;
      dst[6] = p67; dst[7] = p67 >> 8;
      dst[8] = p8;
    }
  }
}

// ---------------- pc conv (fp8 MFMA) ++ horizontal-fused W pack + S zero ----------
// grid 4838: [0,656) pc conv (kc=bb%16, mb=bb/16);
// [656,4787): W -> fp8 Wq2+Wq (2 rows/thread, LDS transpose); [4787,4838): zero S.
__global__ __launch_bounds__(256, 3) void k_pc4(const unsigned short* __restrict__ feat2,
                                                const unsigned char* __restrict__ PCWQ,
                                                __half* __restrict__ pcp,
                                                const float* __restrict__ W,
                                                unsigned char* __restrict__ Wq2,
                                                unsigned char* __restrict__ Wq,
                                                float* __restrict__ S) {
  __shared__ unsigned char shmem[2 * 64 * 104];  // 13312 B (>= 8192 pack tile)
  int bb = blockIdx.x;
  int t = threadIdx.x;

  if (bb >= 4787) {  // S zero
    int idx = (bb - 4787) * 1024 + t * 4;  // 51*1024 = 52224
    *(float4*)(S + idx) = make_float4(0.f, 0.f, 0.f, 0.f);
    return;
  }
  if (bb >= 656) {  // W pack branch (consumed by k_B3/k_A3, after this kernel)
    unsigned char* sq = shmem;  // 64*128 = 8192 B
    size_t base = (size_t)(bb - 656) * 8192;  // 64 rows of 128 floats
    int g = t >> 3, seg = t & 7;
    int r0 = 2 * g, r1 = 2 * g + 1;
    const f32x4* s0 = (const f32x4*)(W + base + r0 * 128 + seg * 16);
    const f32x4* s1 = (const f32x4*)(W + base + r1 * 128 + seg * 16);
    f32x4 a0 = s0[0], a1 = s0[1], a2 = s0[2], a3 = s0[3];
    f32x4 c0 = s1[0], c1 = s1[1], c2 = s1[2], c3 = s1[3];
    unsigned w0[4], w1[4];
    f32x4 va[4] = {a0, a1, a2, a3}, vc[4] = {c0, c1, c2, c3};
#pragma unroll
    for (int j = 0; j < 4; ++j) {
      w0[j] = fp8pair(va[j][0] * 64.f, va[j][1] * 64.f) |
              (fp8pair(va[j][2] * 64.f, va[j][3] * 64.f) << 16);
      w1[j] = fp8pair(vc[j][0] * 64.f, vc[j][1] * 64.f) |
              (fp8pair(vc[j][2] * 64.f, vc[j][3] * 64.f) << 16);
    }
    *(uint4*)(Wq2 + base + r0 * 128 + seg * 16) = make_uint4(w0[0], w0[1], w0[2], w0[3]);
    *(uint4*)(Wq2 + base + r1 * 128 + seg * 16) = make_uint4(w1[0], w1[1], w1[2], w1[3]);
#pragma unroll
    for (int e = 0; e < 16; ++e) {
      int idx = seg * 16 + e, d = idx >> 3, i = idx & 7;
      sq[r0 * 128 + i * 16 + d] = (unsigned char)((w0[e >> 2] >> ((e & 3) * 8)) & 0xffu);
      sq[r1 * 128 + i * 16 + d] = (unsigned char)((w1[e >> 2] >> ((e & 3) * 8)) & 0xffu);
    }
    __syncthreads();
    *(uint4*)(Wq + base + (size_t)t * 16) = ((const uint4*)sq)[t];
    *(uint4*)(Wq + base + 4096 + (size_t)t * 16) = ((const uint4*)sq)[256 + t];
    return;
  }

  // ---- pc conv branch ----
  unsigned char (*lA)[64 * 104] = (unsigned char (*)[64 * 104])shmem;
  int kc = bb & 15, mb = bb >> 4;  // 656 = 41*16
  int lane = t & 63, wv = t >> 6;
  int l15 = lane & 15, lh = lane >> 4;

  {
    uint4 zz = make_uint4(0, 0, 0, 0);
    uint4* z = (uint4*)shmem;
    for (int i = t; i < 2 * 64 * 104 / 16; i += 256) z[i] = zz;
  }
  __syncthreads();
  pc_gather8(feat2, lA[0], mb, kc * 16, t);
  __syncthreads();

  f32x4 acc[4][4];
#pragma unroll
  for (int mf = 0; mf < 4; ++mf)
#pragma unroll
    for (int nf = 0; nf < 4; ++nf) acc[mf][nf] = (f32x4){0.f, 0.f, 0.f, 0.f};

#pragma unroll 1
  for (int cil = 0; cil < 16; ++cil) {
    int ci = kc * 16 + cil;
    int cur = cil & 1;

    i64 bfr[4][3];
    const unsigned char* Bbase = PCWQ + (size_t)ci * 26624 + (wv * 64 + l15) * 104 + lh * 8;
#pragma unroll
    for (int nf = 0; nf < 4; ++nf)
#pragma unroll
      for (int s = 0; s < 3; ++s)
        bfr[nf][s] = *(const i64*)(Bbase + nf * 16 * 104 + s * 32);

    if (cil < 15) pc_gather8(feat2, lA[cur ^ 1], mb, ci + 1, t);

    const unsigned char* arow = lA[cur] + l15 * 104 + lh * 8;
#pragma unroll
    for (int s = 0; s < 3; ++s) {
      i64 a0 = *(const i64*)(arow + s * 32);
      i64 a1 = *(const i64*)(arow + 16 * 104 + s * 32);
      i64 a2 = *(const i64*)(arow + 32 * 104 + s * 32);
      i64 a3 = *(const i64*)(arow + 48 * 104 + s * 32);
      acc[0][0] = __builtin_amdgcn_mfma_f32_16x16x32_fp8_fp8(a0, bfr[0][s], acc[0][0], 0, 0, 0);
      acc[0][1] = __builtin_amdgcn_mfma_f32_16x16x32_fp8_fp8(a0, bfr[1][s], acc[0][1], 0, 0, 0);
      acc[0][2] = __builtin_amdgcn_mfma_f32_16x16x32_fp8_fp8(a0, bfr[2][s], acc[0][2], 0, 0, 0);
      acc[0][3] = __builtin_amdgcn_mfma_f32_16x16x32_fp8_fp8(a0, bfr[3][s], acc[0][3], 0, 0, 0);
      acc[1][0] = __builtin_amdgcn_mfma_f32_16x16x32_fp8_fp8(a1, bfr[0][s], acc[1][0], 0, 0, 0);
      acc[1][1] = __builtin_amdgcn_mfma_f32_16x16x32_fp8_fp8(a1, bfr[1][s], acc[1][1], 0, 0, 0);
      acc[1][2] = __builtin_amdgcn_mfma_f32_16x16x32_fp8_fp8(a1, bfr[2][s], acc[1][2], 0, 0, 0);
      acc[1][3] = __builtin_amdgcn_mfma_f32_16x16x32_fp8_fp8(a1, bfr[3][s], acc[1][3], 0, 0, 0);
      acc[2][0] = __builtin_amdgcn_mfma_f32_16x16x32_fp8_fp8(a2, bfr[0][s], acc[2][0], 0, 0, 0);
      acc[2][1] = __builtin_amdgcn_mfma_f32_16x16x32_fp8_fp8(a2, bfr[1][s], acc[2][1], 0, 0, 0);
      acc[2][2] = __builtin_amdgcn_mfma_f32_16x16x32_fp8_fp8(a2, bfr[2][s], acc[2][2], 0, 0, 0);
      acc[2][3] = __builtin_amdgcn_mfma_f32_16x16x32_fp8_fp8(a2, bfr[3][s], acc[2][3], 0, 0, 0);
      acc[3][0] = __builtin_amdgcn_mfma_f32_16x16x32_fp8_fp8(a3, bfr[0][s], acc[3][0], 0, 0, 0);
      acc[3][1] = __builtin_amdgcn_mfma_f32_16x16x32_fp8_fp8(a3, bfr[1][s], acc[3][1], 0, 0, 0);
      acc[3][2] = __builtin_amdgcn_mfma_f32_16x16x32_fp8_fp8(a3, bfr[2][s], acc[3][2], 0, 0, 0);
      acc[3][3] = __builtin_amdgcn_mfma_f32_16x16x32_fp8_fp8(a3, bfr[3][s], acc[3][3], 0, 0, 0);
    }
    __syncthreads();
  }

#pragma unroll
  for (int mf = 0; mf < 4; ++mf) {
    int gm = mb * 64 + mf * 16 + lh * 4;
    if (gm < 2592) {
      __half* dst = pcp + (size_t)kc * 663552 + (size_t)gm * 256 + wv * 64 + l15;
#pragma unroll
      for (int nf = 0; nf < 4; ++nf)
#pragma unroll
        for (int r = 0; r < 4; ++r)
          dst[(size_t)r * 256 + nf * 16] = __float2half(acc[mf][nf][r]);
    }
  }
}

// ---------------- fused transpose-reduce-squash: pcp(16 fp16 slices) -> u2 ----------------
__global__ __launch_bounds__(256) void k_rs(const __half* __restrict__ pcp,
                                            const float* __restrict__ pcb,
                                            float* __restrict__ u2) {
  __shared__ float tile[81 * 17];
  int b = blockIdx.x;    // 32
  int cog = blockIdx.y;  // 16
  int c0 = cog * 16;
  int t = threadIdx.x;

  for (int e = t; e < 1296; e += 256) {
    int p = e >> 4, col = e & 15;
    const __half* base = pcp + (size_t)(b * 81 + p) * 256 + c0 + col;
    float s = 0.f;
#pragma unroll
    for (int c = 0; c < 16; ++c) s += __half2float(base[(size_t)c * 663552]);
    tile[p * 17 + col] = pcb[c0 + col] + s * 0.015625f;  // /64 (W x64)
  }
  __syncthreads();

  if (t < 162) {
    float v[8];
    float sq = 0.f;
#pragma unroll
    for (int i = 0; i < 8; ++i) {
      int g = t * 8 + i;
      int col = g / 81, p = g - col * 81;
      v[i] = tile[p * 17 + col];
      sq += v[i] * v[i];
    }
    float sc = (sq / (1.f + sq)) / sqrtf(sq + 1e-8f);
    int n = cog * 162 + t;
    float4* dst = (float4*)(u2 + ((size_t)b * 2592 + n) * 8);
    dst[0] = make_float4(v[0] * sc, v[1] * sc, v[2] * sc, v[3] * sc);
    dst[1] = make_float4(v[4] * sc, v[5] * sc, v[6] * sc, v[7] * sc);
  }
}

// ---------------- routing kernel A3 (fp8 MFMA, o-split x3): E + partial den ----------------
__global__ __launch_bounds__(128) void k_A3(const unsigned char* __restrict__ Wq,
                                            const float* __restrict__ u2,
                                            const unsigned char* __restrict__ vq,
                                            __half* __restrict__ cT,
                                            float* __restrict__ den) {
  int nb = blockIdx.x;   // 648
  int ch = blockIdx.y;   // 3
  int o0 = ch * 34;
  int t = threadIdx.x, wv = t >> 6, lane = t & 63;
  int l15 = lane & 15, g = lane >> 4;
  int n0 = nb * 4 + 2 * wv;
  int nl = g >> 1, ih = (g & 1) * 4;

  float4 u0 = *(const float4*)(u2 + (((size_t)l15 * 2592 + n0 + nl) * 8 + ih));
  float4 u1 = *(const float4*)(u2 + (((size_t)(l15 + 16) * 2592 + n0 + nl) * 8 + ih));

  int nlA = l15 >> 3, iA = l15 & 7;
  const unsigned char* Ap = Wq + (((size_t)(n0 + nlA)) * 8 + iA) * 16 + (g & 1) * 8 +
                            (size_t)o0 * 331776;
  const unsigned char* B0p = vq + (size_t)l15 * 16 + (g & 1) * 8 + (size_t)o0 * 512;
  bool act = (g < 2);

  float den0 = 0.f, den1 = 0.f;
#pragma unroll 2
  for (int oo = 0; oo < 34; ++oo) {
    i64 a = 0, b0 = 0, b1 = 0;
    if (act) {
      a  = *(const i64*)(Ap + (size_t)oo * 331776);
      b0 = *(const i64*)(B0p + (size_t)oo * 512);
      b1 = *(const i64*)(B0p + (size_t)oo * 512 + 256);
    }
    f32x4 d0 = {0.f, 0.f, 0.f, 0.f}, d1 = {0.f, 0.f, 0.f, 0.f};
    d0 = __builtin_amdgcn_mfma_f32_16x16x32_fp8_fp8(a, b0, d0, 0, 0, 0);
    d1 = __builtin_amdgcn_mfma_f32_16x16x32_fp8_fp8(a, b1, d1, 0, 0, 0);
    float p0 = d0[0] * u0.x + d0[1] * u0.y + d0[2] * u0.z + d0[3] * u0.w;
    float p1 = d1[0] * u1.x + d1[1] * u1.y + d1[2] * u1.z + d1[3] * u1.w;
    p0 += __shfl_xor(p0, 16);
    p1 += __shfl_xor(p1, 16);
    p0 *= 1.52587890625e-05f;  // / (64 * 1024)
    p1 *= 1.52587890625e-05f;
    float e0 = __expf(p0), e1 = __expf(p1);
    den0 += e0; den1 += e1;
    if ((g & 1) == 0) {
      __half* dst = cT + ((size_t)(o0 + oo) * 2592 + n0 + nl) * 32 + l15;
      dst[0]  = __float2half(e0);
      dst[16] = __float2half(e1);
    }
  }
  if ((g & 1) == 0) {
    atomicAdd(den + (n0 + nl) * 32 + l15, den0);
    atomicAdd(den + (n0 + nl) * 32 + l15 + 16, den1);
  }
}

// ---------------- routing kernel B (fp8 MFMA): s = sum (E/den)*xhat ----------------
__device__ __forceinline__ i64 cu_pack8(float c, float4 a, float4 b) {
  union { unsigned u[2]; i64 v; } r;
  r.u[0] = fp8pair(c * a.x, c * a.y) | (fp8pair(c * a.z, c * a.w) << 16);
  r.u[1] = fp8pair(c * b.x, c * b.y) | (fp8pair(c * b.z, c * b.w) << 16);
  return r.v;
}

template <bool HASC>
__global__ __launch_bounds__(256) void k_B3(const unsigned char* __restrict__ Wq2,
                                            const float* __restrict__ u2,
                                            const __half* __restrict__ cT,
                                            const float* __restrict__ den,
                                            float* __restrict__ s) {
  int o = blockIdx.x, kc = blockIdx.y;  // (102, 12)
  int t = threadIdx.x, lane = t & 63, wv = t >> 6;
  int l15 = lane & 15, h = lane >> 4;

  f32x4 acc0 = {0.f, 0.f, 0.f, 0.f}, acc1 = {0.f, 0.f, 0.f, 0.f};

#pragma unroll 1
  for (int st = wv; st < 54; st += 4) {
    int n = kc * 216 + st * 4 + h;
    i64 aq = *(const i64*)(Wq2 + (((size_t)o * 2592 + n) * 16 + l15) * 8);

    const float4* u0p = (const float4*)(u2 + ((size_t)l15 * 2592 + n) * 8);
    float4 u0a = u0p[0], u0b = u0p[1];
    const float4* u1p = (const float4*)(u2 + ((size_t)(l15 + 16) * 2592 + n) * 8);
    float4 u1a = u1p[0], u1b = u1p[1];

    float c0 = 16.0f, c1 = 16.0f;
    if (HASC) {
      const __half* cp = cT + ((size_t)o * 2592 + n) * 32;
      float i0 = rcpf(den[n * 32 + l15]);
      float i1 = rcpf(den[n * 32 + l15 + 16]);
      c0 = 16.0f * __half2float(cp[l15]) * i0;
      c1 = 16.0f * __half2float(cp[l15 + 16]) * i1;
    }
    i64 b0 = cu_pack8(c0, u0a, u0b);
    i64 b1 = cu_pack8(c1, u1a, u1b);

    acc0 = __builtin_amdgcn_mfma_f32_16x16x32_fp8_fp8(aq, b0, acc0, 0, 0, 0);
    acc1 = __builtin_amdgcn_mfma_f32_16x16x32_fp8_fp8(aq, b1, acc1, 0, 0, 0);
  }

#pragma unroll
  for (int r = 0; r < 4; ++r) {
    atomicAdd(s + ((size_t)l15 * 102 + o) * 16 + h * 4 + r, acc0[r]);
    atomicAdd(s + ((size_t)(l15 + 16) * 102 + o) * 16 + h * 4 + r, acc1[r]);
  }
}

// ---------------- squash v; optional fp8 vsum; optional S re-zero + den zero ----------------
__global__ void k_R(const float* __restrict__ s, float scale,
                    float* __restrict__ vout, const float* __restrict__ addin,
                    unsigned char* __restrict__ vsq, float* __restrict__ szero,
                    float* __restrict__ dzero) {
  int t = blockIdx.x * 256 + threadIdx.x;  // grid 13*256 = 3328
  if (dzero) {
    for (int i = t; i < 82944; i += 3328) dzero[i] = 0.f;
  }
  if (t >= 3264) return;
  const float* sp = s + t * 16;
  float r[16];
  float sq = 0.f;
#pragma unroll
  for (int d = 0; d < 16; ++d) {
    r[d] = sp[d] * scale;
    sq += r[d] * r[d];
  }
  if (szero) {
#pragma unroll
    for (int d = 0; d < 16; ++d) szero[t * 16 + d] = 0.f;
  }
  float sc = (sq / (1.f + sq)) / sqrtf(sq + 1e-8f);
  float vv[16];
#pragma unroll
  for (int d = 0; d < 16; ++d) {
    vv[d] = r[d] * sc;
    vout[t * 16 + d] = vv[d];
  }
  if (vsq) {
    int b = t / 102, o = t - b * 102;
    float w[16];
#pragma unroll
    for (int d = 0; d < 16; ++d)
      w[d] = (addin ? (addin[t * 16 + d] + vv[d]) : vv[d]) * 1024.f;
    unsigned words[4];
#pragma unroll
    for (int q = 0; q < 4; ++q)
      words[q] = fp8pair(w[4 * q], w[4 * q + 1]) | (fp8pair(w[4 * q + 2], w[4 * q + 3]) << 16);
    *(uint4*)(vsq + ((size_t)o * 32 + b) * 16) =
        make_uint4(words[0], words[1], words[2], words[3]);
  }
}

// ---------------- fused fc1+fc2: block = bq (4 batch items), h1 in LDS ----------------
__global__ __launch_bounds__(512) void k_fc12(const float* __restrict__ v2,
                                              const int* __restrict__ tgt,
                                              const float* __restrict__ w1,
                                              const float* __restrict__ b1,
                                              const float* __restrict__ w2,
                                              const float* __restrict__ b2,
                                              float* __restrict__ h2T) {
  __shared__ float h1s[4][512];
  int bq = blockIdx.x;  // 8
  int t = threadIdx.x;  // 512
#pragma unroll
  for (int bi = 0; bi < 4; ++bi) {
    int b = bq * 4 + bi;
    int tb = tgt[b];
    float acc = b1[t];
    const float* vv = v2 + (b * 102 + tb) * 16;
    const float* wr = w1 + (tb * 16) * 512 + t;
#pragma unroll
    for (int d = 0; d < 16; ++d) acc += vv[d] * wr[d * 512];
    h1s[bi][t] = fmaxf(acc, 0.f);
  }
  __syncthreads();
  float a0[4], a1[4];
#pragma unroll
  for (int bi = 0; bi < 4; ++bi) { a0[bi] = b2[t]; a1[bi] = b2[t + 512]; }
  for (int k = 0; k < 512; ++k) {
    float w0 = w2[k * 1024 + t], w1v = w2[k * 1024 + t + 512];
#pragma unroll
    for (int bi = 0; bi < 4; ++bi) {
      float h = h1s[bi][k];
      a0[bi] += h * w0;
      a1[bi] += h * w1v;
    }
  }
  float4 o0, o1;
  o0.x = fmaxf(a0[0], 0.f); o0.y = fmaxf(a0[1], 0.f);
  o0.z = fmaxf(a0[2], 0.f); o0.w = fmaxf(a0[3], 0.f);
  o1.x = fmaxf(a1[0], 0.f); o1.y = fmaxf(a1[1], 0.f);
  o1.z = fmaxf(a1[2], 0.f); o1.w = fmaxf(a1[3], 0.f);
  *(float4*)(h2T + t * 32 + bq * 4) = o0;
  *(float4*)(h2T + (t + 512) * 32 + bq * 4) = o1;
}

__global__ void k_fc3a(const float* __restrict__ h2T, const float* __restrict__ w3,
                       float* __restrict__ p) {
  int j = blockIdx.x * 128 + threadIdx.x;
  int ky = blockIdx.y;
  float acc[32];
#pragma unroll
  for (int i = 0; i < 32; ++i) acc[i] = 0.f;
  int k0 = ky * 256;
  for (int k = k0; k < k0 + 256; ++k) {
    float wv = w3[(size_t)k * 37632 + j];
    const float4* hp = (const float4*)(h2T + k * 32);
#pragma unroll
    for (int q = 0; q < 8; ++q) {
      float4 h = hp[q];
      acc[q * 4 + 0] += h.x * wv; acc[q * 4 + 1] += h.y * wv;
      acc[q * 4 + 2] += h.z * wv; acc[q * 4 + 3] += h.w * wv;
    }
  }
#pragma unroll
  for (int i = 0; i < 32; ++i)
    p[((size_t)ky * 32 + i) * 37632 + j] = acc[i];
}

__global__ void k_fc3b(const float* __restrict__ p, const float* __restrict__ b3,
                       float* __restrict__ out) {
  int j = blockIdx.x * 256 + threadIdx.x;
  float bv = b3[j];
#pragma unroll 1
  for (int b = 0; b < 32; ++b) {
    float s = bv + p[(size_t)b * 37632 + j] + p[(size_t)(32 + b) * 37632 + j] +
              p[(size_t)(64 + b) * 37632 + j] + p[(size_t)(96 + b) * 37632 + j];
    out[52224 + (size_t)b * 37632 + j] = 1.0f / (1.0f + __expf(-s));
  }
}

// ---------------- host ----------------
extern "C" void kernel_launch(void* const* d_in, const int* in_sizes, int n_in,
                              void* d_out, int out_size, void* d_ws, size_t ws_size,
                              hipStream_t stream) {
  const float* x       = (const float*)d_in[0];
  const int*   targets = (const int*)d_in[1];
  const float* conv1_w = (const float*)d_in[2];
  const float* conv1_b = (const float*)d_in[3];
  const float* pc_w    = (const float*)d_in[4];
  const float* pc_b    = (const float*)d_in[5];
  const float* W       = (const float*)d_in[6];
  const float* fc1_w   = (const float*)d_in[7];
  const float* fc1_b   = (const float*)d_in[8];
  const float* fc2_w   = (const float*)d_in[9];
  const float* fc2_b   = (const float*)d_in[10];
  const float* fc3_w   = (const float*)d_in[11];
  const float* fc3_b   = (const float*)d_in[12];
  float* out = (float*)d_out;
  float* ws = (float*)d_ws;

  unsigned short* FEAT2 = (unsigned short*)(ws + OFF_FEAT);
  unsigned short* C1WB = (unsigned short*)(ws + OFF_C1WT);
  unsigned char* PCWQ = (unsigned char*)(ws + OFF_PCWQ);
  __half* PCP = (__half*)(ws + OFF_PCP);
  unsigned char* WQ2 = (unsigned char*)(ws + OFF_WQ2);
  unsigned char* WQ  = (unsigned char*)(ws + OFF_WQ);
  float* U2   = ws + OFF_U2;
  __half* CT  = (__half*)(ws + OFF_CT);
  float* DEN  = ws + OFF_DEN;
  float* S    = ws + OFF_S;
  float* V0   = ws + OFF_V0;
  float* V1   = ws + OFF_V1;
  unsigned char* VSQ = (unsigned char*)(ws + OFF_VSQ);
  float* H2T  = ws + OFF_H2T;
  float* FC3P = ws + OFF_FC3P;

  // conv1 pack (consumed by k_c1m)
  k_pack0<<<dim3(256), 128, 0, stream>>>(conv1_w, C1WB);

  // conv1 (bf16 MFMA) ++ pc_w pack fused
  k_c1m<<<dim3(2432), 256, 0, stream>>>(x, C1WB, conv1_b, FEAT2, pc_w, PCWQ);

  // pc conv (fp8 MFMA) ++ W pack + S zero fused
  k_pc4<<<dim3(4838), 256, 0, stream>>>(FEAT2, PCWQ, PCP, W, WQ2, WQ, S);
  k_rs<<<dim3(32, 16), 256, 0, stream>>>(PCP, pc_b, U2);

  // ---- routing ---- (scales: W x64, cu x16 -> /1024; vq x1024 -> logits /65536)
  k_B3<false><<<dim3(102, 12), 256, 0, stream>>>(WQ2, U2, nullptr, nullptr, S);
  k_R<<<dim3(13), 256, 0, stream>>>(S, 1.0f / (102.0f * 1024.0f), V0, nullptr, VSQ, S, DEN);

  k_A3<<<dim3(648, 3), 128, 0, stream>>>(WQ, U2, VSQ, CT, DEN);
  k_B3<true><<<dim3(102, 12), 256, 0, stream>>>(WQ2, U2, CT, DEN, S);
  k_R<<<dim3(13), 256, 0, stream>>>(S, 1.0f / 1024.0f, V1, V0, VSQ, S, DEN);  // vsq = v0+v1

  k_A3<<<dim3(648, 3), 128, 0, stream>>>(WQ, U2, VSQ, CT, DEN);
  k_B3<true><<<dim3(102, 12), 256, 0, stream>>>(WQ2, U2, CT, DEN, S);
  k_R<<<dim3(13), 256, 0, stream>>>(S, 1.0f / 1024.0f, out, nullptr, nullptr, nullptr, nullptr);

  // ---- reconstruction ----
  k_fc12<<<dim3(8), 512, 0, stream>>>(out, targets, fc1_w, fc1_b, fc2_w, fc2_b, H2T);
  k_fc3a<<<dim3(294, 4), 128, 0, stream>>>(H2T, fc3_w, FC3P);
  k_fc3b<<<dim3(147), 256, 0, stream>>>(FC3P, fc3_b, out);
}

// Round 18
// 541.191 us; speedup vs baseline: 1.0250x; 1.0028x over previous
//
#include <hip/hip_runtime.h>
#include <hip/hip_fp16.h>
#include <math.h>

// ---------------- sizes ----------------
#define B32   32
#define OCLS  102
#define NCAPS 2592

// ---------------- ws map (floats) -- ws is 616 MB; flat, no overlays ----
#define OFF_FEAT   0u               // feat2[b][h][co][w36] bf16
#define OFF_C1WT   10027008u        // bf16 conv1 pack
#define OFF_PCWQ   10076160u        // fp8 pc pack
#define OFF_PCP    11780096u        // fp16 partials 16 slices
#define OFF_WQ2    17088512u        // fp8 W pack [o][n][d][i]
#define OFF_WQ     25555456u        // fp8 W pack [o][n][i][d]
#define OFF_U2     34022400u
#define OFF_CT     34685952u        // fp16 E[o][n][b]
#define OFF_DEN    38916096u        // f32 den[n][b]
#define OFF_S      38999040u
#define OFF_V0     39051264u
#define OFF_V1     39103488u
#define OFF_VSQ    39155712u        // fp8 vsum x1024
#define OFF_H2T    39185152u
#define OFF_FC3P   39217920u        // -> end 44,034,816 (176MB < 616MB)

typedef __attribute__((ext_vector_type(8))) short short8;
typedef __attribute__((ext_vector_type(4))) float f32x4;
typedef long long i64;

__device__ __forceinline__ unsigned short f2b(float f) {
  union { float f; unsigned u; } v; v.f = f;
  unsigned r = v.u + 0x7fffu + ((v.u >> 16) & 1u);
  return (unsigned short)(r >> 16);
}

__device__ __forceinline__ float b2f(unsigned short h) {
  union { unsigned u; float f; } v; v.u = ((unsigned)h) << 16;
  return v.f;
}

// float -> OCP e4m3fn (RNE, flush<2^-6, clamp) -- software fallback
__device__ __forceinline__ unsigned f2q_fast(float x) {
  union { float f; unsigned u; } v; v.f = x;
  unsigned s = (v.u >> 24) & 0x80u;
  unsigned au = v.u & 0x7fffffffu;
  if (au < 0x3c800000u) return s;
  if (au >= 0x43e00000u) return s | 0x7eu;
  unsigned r = au + 0x7ffffu + ((au >> 20) & 1u);
  unsigned e = (r >> 23) - 120u;
  unsigned m = (r >> 20) & 7u;
  return s | (e << 3) | m;
}

__device__ __forceinline__ unsigned fp8pair(float a, float b) {
#if __has_builtin(__builtin_amdgcn_cvt_pk_fp8_f32)
  return (unsigned)__builtin_amdgcn_cvt_pk_fp8_f32(a, b, 0, false) & 0xffffu;
#else
  return f2q_fast(a) | (f2q_fast(b) << 8);
#endif
}

__device__ __forceinline__ float rcpf(float x) {
#if __has_builtin(__builtin_amdgcn_rcpf)
  return __builtin_amdgcn_rcpf(x);
#else
  return 1.0f / x;
#endif
}

// ---------------- k_pack0: conv1_w -> bf16 C1WB (must precede k_c1m) ----------------
__global__ __launch_bounds__(128) void k_pack0(const float* __restrict__ conv1_w,
                                               unsigned short* __restrict__ C1WB) {
  int co = blockIdx.x;
  int t = threadIdx.x;
#pragma unroll
  for (int ci = 0; ci < 3; ++ci) {
    float v = (t < 121) ? conv1_w[co * 363 + ci * 121 + t] : 0.f;
    C1WB[(ci * 256 + co) * 128 + t] = f2b(v);
  }
}

// ---------------- conv1 (bf16 MFMA, co-split) ++ horizontal-fused pc_w pack ----------
// grid 2432: [0,2176) conv blocks (bx=bb>>1, hf=bb&1); [2176,2432) pc_w->fp8 PCWQ.
__global__ __launch_bounds__(256) void k_c1m(const float* __restrict__ x,
                                             const unsigned short* __restrict__ C1WB,
                                             const float* __restrict__ bias,
                                             unsigned short* __restrict__ feat2,
                                             const float* __restrict__ pc_w,
                                             unsigned char* __restrict__ PCWQ) {
  __shared__ unsigned short sh[48 * 128 + 128 * 128];
  int bb = blockIdx.x;
  int t = threadIdx.x;

  if (bb >= 2176) {  // pc_w pack branch (consumed by next kernel)
    int co = bb - 2176;
    for (int e = t; e < 20736; e += 256) {
      int ci = e / 81, tap = e - ci * 81;
      PCWQ[(size_t)ci * 26624 + co * 104 + tap] =
          (unsigned char)f2q_fast(pc_w[(size_t)co * 20736 + e] * 64.f);
    }
    for (int tap = 81; tap < 104; ++tap)
      PCWQ[(size_t)t * 26624 + co * 104 + tap] = 0;
    return;
  }

  unsigned short* lA = sh;
  unsigned short* lB = sh + 48 * 128;
  unsigned short* obuf = sh + 48 * 128;

  int bx = bb >> 1;
  int hf = bb & 1;
  int b = bx / 34, ho = bx % 34;
  int lane = t & 63, wv = t >> 6;
  int l15 = lane & 15, lh = lane >> 4;
  int rx = l15 & 7;

  {
    uint4 zz = make_uint4(0, 0, 0, 0);
    uint4* z = (uint4*)lA;
    for (int i = t; i < 48 * 128 / 8; i += 256) z[i] = zz;
  }
  __syncthreads();

  f32x4 acc[3][2];
#pragma unroll
  for (int mf = 0; mf < 3; ++mf)
#pragma unroll
    for (int nf = 0; nf < 2; ++nf) acc[mf][nf] = (f32x4){0.f, 0.f, 0.f, 0.f};

#pragma unroll 1
  for (int ci = 0; ci < 3; ++ci) {
    {
      const uint4* Bsrc = (const uint4*)(C1WB + ci * 32768 + hf * 16384);
#pragma unroll
      for (int i = 0; i < 8; ++i) {
        int f = i * 256 + t;
        int row = f >> 4, cu = f & 15;
        ((uint4*)lB)[row * 16 + (cu ^ (row & 7))] = Bsrc[f];
      }
    }
    for (int tk = t; tk < 374; tk += 256) {
      int kh = tk / 34, wo = tk - kh * 34;
      const float* src = x + ((size_t)(b * 3 + ci) * 112 + ho * 3 + kh) * 112 + wo * 3;
#pragma unroll
      for (int j = 0; j < 11; ++j) {
        int tap = kh * 11 + j;
        int cu = tap >> 3;
        lA[wo * 128 + (((cu ^ (wo & 7)) << 3) | (tap & 7))] = f2b(src[j]);
      }
    }
    __syncthreads();

#pragma unroll
    for (int s = 0; s < 4; ++s) {
      int cub = ((s * 4 + lh) ^ rx) << 3;
      short8 a0 = *(const short8*)(lA + (0 + l15) * 128 + cub);
      short8 a1 = *(const short8*)(lA + (16 + l15) * 128 + cub);
      short8 a2 = *(const short8*)(lA + (32 + l15) * 128 + cub);
      short8 b0 = *(const short8*)(lB + (wv * 32 + 0 + l15) * 128 + cub);
      short8 b1 = *(const short8*)(lB + (wv * 32 + 16 + l15) * 128 + cub);
      acc[0][0] = __builtin_amdgcn_mfma_f32_16x16x32_bf16(a0, b0, acc[0][0], 0, 0, 0);
      acc[0][1] = __builtin_amdgcn_mfma_f32_16x16x32_bf16(a0, b1, acc[0][1], 0, 0, 0);
      acc[1][0] = __builtin_amdgcn_mfma_f32_16x16x32_bf16(a1, b0, acc[1][0], 0, 0, 0);
      acc[1][1] = __builtin_amdgcn_mfma_f32_16x16x32_bf16(a1, b1, acc[1][1], 0, 0, 0);
      acc[2][0] = __builtin_amdgcn_mfma_f32_16x16x32_bf16(a2, b0, acc[2][0], 0, 0, 0);
      acc[2][1] = __builtin_amdgcn_mfma_f32_16x16x32_bf16(a2, b1, acc[2][1], 0, 0, 0);
    }
    __syncthreads();
  }

  float bv[2];
#pragma unroll
  for (int nf = 0; nf < 2; ++nf) bv[nf] = bias[hf * 128 + wv * 32 + nf * 16 + l15];
#pragma unroll
  for (int mf = 0; mf < 3; ++mf)
#pragma unroll
    for (int nf = 0; nf < 2; ++nf)
#pragma unroll
      for (int r = 0; r < 4; ++r) {
        int wo = mf * 16 + lh * 4 + r;
        if (wo < 36)
          obuf[(wv * 32 + nf * 16 + l15) * 36 + wo] =
              f2b(fmaxf(acc[mf][nf][r] + bv[nf], 0.f));
      }
  __syncthreads();
  uint4* dst = (uint4*)(feat2 + (size_t)bx * 9216 + hf * 4608);
  const uint4* srcb = (const uint4*)obuf;
  for (int i = t; i < 576; i += 256) dst[i] = srcb[i];
}

// ---------------- pc conv gather (bf16 feat2 -> fp8) ----------------
__device__ __forceinline__ void pc_gather8(const unsigned short* __restrict__ feat2,
                                           unsigned char* __restrict__ dstbuf,
                                           int mb, int ci, int t) {
  for (int task = t; task < 576; task += 256) {
    int m = task / 9, kh = task - m * 9;
    int gm = mb * 64 + m;
    if (gm < 2592) {
      int b = gm / 81, p = gm - b * 81;
      int ho = p / 9, wo = p - ho * 9;
      const unsigned short* src =
          feat2 + ((size_t)(b * 34 + ho * 3 + kh) * 256 + ci) * 36 + wo * 3;
      unsigned char* dst = dstbuf + m * 104 + kh * 9;
      unsigned p01 = fp8pair(b2f(src[0]), b2f(src[1]));
      unsigned p23 = fp8pair(b2f(src[2]), b2f(src[3]));
      unsigned p45 = fp8pair(b2f(src[4]), b2f(src[5]));
      unsigned p67 = fp8pair(b2f(src[6]), b2f(src[7]));
      unsigned p8  = fp8pair(b2f(src[8]), 0.f);
      dst[0] = p01; dst[1] = p01 >> 8;
      dst[2] = p23; dst[3] = p23 >> 8;
      dst[4] = p45; dst[5] = p45 >> 8;
      dst[6] = p67; dst[7] = p67 >> 8;
      dst[8] = p8;
    }
  }
}

// ---------------- pc conv (fp8 MFMA) ++ horizontal-fused W pack + S zero ----------
// grid 4838: [0,656) pc conv (kc=bb%16, mb=bb/16);
// [656,4787): W -> fp8 Wq2+Wq (2 rows/thread, LDS transpose); [4787,4838): zero S.
__global__ __launch_bounds__(256, 3) void k_pc4(const unsigned short* __restrict__ feat2,
                                                const unsigned char* __restrict__ PCWQ,
                                                __half* __restrict__ pcp,
                                                const float* __restrict__ W,
                                                unsigned char* __restrict__ Wq2,
                                                unsigned char* __restrict__ Wq,
                                                float* __restrict__ S) {
  __shared__ unsigned char shmem[2 * 64 * 104];  // 13312 B (>= 8192 pack tile)
  int bb = blockIdx.x;
  int t = threadIdx.x;

  if (bb >= 4787) {  // S zero
    int idx = (bb - 4787) * 1024 + t * 4;  // 51*1024 = 52224
    *(float4*)(S + idx) = make_float4(0.f, 0.f, 0.f, 0.f);
    return;
  }
  if (bb >= 656) {  // W pack branch (consumed by k_B3/k_A3, after this kernel)
    unsigned char* sq = shmem;  // 64*128 = 8192 B
    size_t base = (size_t)(bb - 656) * 8192;  // 64 rows of 128 floats
    int g = t >> 3, seg = t & 7;
    int r0 = 2 * g, r1 = 2 * g + 1;
    const f32x4* s0 = (const f32x4*)(W + base + r0 * 128 + seg * 16);
    const f32x4* s1 = (const f32x4*)(W + base + r1 * 128 + seg * 16);
    f32x4 a0 = s0[0], a1 = s0[1], a2 = s0[2], a3 = s0[3];
    f32x4 c0 = s1[0], c1 = s1[1], c2 = s1[2], c3 = s1[3];
    unsigned w0[4], w1[4];
    f32x4 va[4] = {a0, a1, a2, a3}, vc[4] = {c0, c1, c2, c3};
#pragma unroll
    for (int j = 0; j < 4; ++j) {
      w0[j] = fp8pair(va[j][0] * 64.f, va[j][1] * 64.f) |
              (fp8pair(va[j][2] * 64.f, va[j][3] * 64.f) << 16);
      w1[j] = fp8pair(vc[j][0] * 64.f, vc[j][1] * 64.f) |
              (fp8pair(vc[j][2] * 64.f, vc[j][3] * 64.f) << 16);
    }
    *(uint4*)(Wq2 + base + r0 * 128 + seg * 16) = make_uint4(w0[0], w0[1], w0[2], w0[3]);
    *(uint4*)(Wq2 + base + r1 * 128 + seg * 16) = make_uint4(w1[0], w1[1], w1[2], w1[3]);
#pragma unroll
    for (int e = 0; e < 16; ++e) {
      int idx = seg * 16 + e, d = idx >> 3, i = idx & 7;
      sq[r0 * 128 + i * 16 + d] = (unsigned char)((w0[e >> 2] >> ((e & 3) * 8)) & 0xffu);
      sq[r1 * 128 + i * 16 + d] = (unsigned char)((w1[e >> 2] >> ((e & 3) * 8)) & 0xffu);
    }
    __syncthreads();
    *(uint4*)(Wq + base + (size_t)t * 16) = ((const uint4*)sq)[t];
    *(uint4*)(Wq + base + 4096 + (size_t)t * 16) = ((const uint4*)sq)[256 + t];
    return;
  }

  // ---- pc conv branch ----
  unsigned char (*lA)[64 * 104] = (unsigned char (*)[64 * 104])shmem;
  int kc = bb & 15, mb = bb >> 4;  // 656 = 41*16
  int lane = t & 63, wv = t >> 6;
  int l15 = lane & 15, lh = lane >> 4;

  {
    uint4 zz = make_uint4(0, 0, 0, 0);
    uint4* z = (uint4*)shmem;
    for (int i = t; i < 2 * 64 * 104 / 16; i += 256) z[i] = zz;
  }
  __syncthreads();
  pc_gather8(feat2, lA[0], mb, kc * 16, t);
  __syncthreads();

  f32x4 acc[4][4];
#pragma unroll
  for (int mf = 0; mf < 4; ++mf)
#pragma unroll
    for (int nf = 0; nf < 4; ++nf) acc[mf][nf] = (f32x4){0.f, 0.f, 0.f, 0.f};

#pragma unroll 1
  for (int cil = 0; cil < 16; ++cil) {
    int ci = kc * 16 + cil;
    int cur = cil & 1;

    i64 bfr[4][3];
    const unsigned char* Bbase = PCWQ + (size_t)ci * 26624 + (wv * 64 + l15) * 104 + lh * 8;
#pragma unroll
    for (int nf = 0; nf < 4; ++nf)
#pragma unroll
      for (int s = 0; s < 3; ++s)
        bfr[nf][s] = *(const i64*)(Bbase + nf * 16 * 104 + s * 32);

    if (cil < 15) pc_gather8(feat2, lA[cur ^ 1], mb, ci + 1, t);

    const unsigned char* arow = lA[cur] + l15 * 104 + lh * 8;
#pragma unroll
    for (int s = 0; s < 3; ++s) {
      i64 a0 = *(const i64*)(arow + s * 32);
      i64 a1 = *(const i64*)(arow + 16 * 104 + s * 32);
      i64 a2 = *(const i64*)(arow + 32 * 104 + s * 32);
      i64 a3 = *(const i64*)(arow + 48 * 104 + s * 32);
      acc[0][0] = __builtin_amdgcn_mfma_f32_16x16x32_fp8_fp8(a0, bfr[0][s], acc[0][0], 0, 0, 0);
      acc[0][1] = __builtin_amdgcn_mfma_f32_16x16x32_fp8_fp8(a0, bfr[1][s], acc[0][1], 0, 0, 0);
      acc[0][2] = __builtin_amdgcn_mfma_f32_16x16x32_fp8_fp8(a0, bfr[2][s], acc[0][2], 0, 0, 0);
      acc[0][3] = __builtin_amdgcn_mfma_f32_16x16x32_fp8_fp8(a0, bfr[3][s], acc[0][3], 0, 0, 0);
      acc[1][0] = __builtin_amdgcn_mfma_f32_16x16x32_fp8_fp8(a1, bfr[0][s], acc[1][0], 0, 0, 0);
      acc[1][1] = __builtin_amdgcn_mfma_f32_16x16x32_fp8_fp8(a1, bfr[1][s], acc[1][1], 0, 0, 0);
      acc[1][2] = __builtin_amdgcn_mfma_f32_16x16x32_fp8_fp8(a1, bfr[2][s], acc[1][2], 0, 0, 0);
      acc[1][3] = __builtin_amdgcn_mfma_f32_16x16x32_fp8_fp8(a1, bfr[3][s], acc[1][3], 0, 0, 0);
      acc[2][0] = __builtin_amdgcn_mfma_f32_16x16x32_fp8_fp8(a2, bfr[0][s], acc[2][0], 0, 0, 0);
      acc[2][1] = __builtin_amdgcn_mfma_f32_16x16x32_fp8_fp8(a2, bfr[1][s], acc[2][1], 0, 0, 0);
      acc[2][2] = __builtin_amdgcn_mfma_f32_16x16x32_fp8_fp8(a2, bfr[2][s], acc[2][2], 0, 0, 0);
      acc[2][3] = __builtin_amdgcn_mfma_f32_16x16x32_fp8_fp8(a2, bfr[3][s], acc[2][3], 0, 0, 0);
      acc[3][0] = __builtin_amdgcn_mfma_f32_16x16x32_fp8_fp8(a3, bfr[0][s], acc[3][0], 0, 0, 0);
      acc[3][1] = __builtin_amdgcn_mfma_f32_16x16x32_fp8_fp8(a3, bfr[1][s], acc[3][1], 0, 0, 0);
      acc[3][2] = __builtin_amdgcn_mfma_f32_16x16x32_fp8_fp8(a3, bfr[2][s], acc[3][2], 0, 0, 0);
      acc[3][3] = __builtin_amdgcn_mfma_f32_16x16x32_fp8_fp8(a3, bfr[3][s], acc[3][3], 0, 0, 0);
    }
    __syncthreads();
  }

#pragma unroll
  for (int mf = 0; mf < 4; ++mf) {
    int gm = mb * 64 + mf * 16 + lh * 4;
    if (gm < 2592) {
      __half* dst = pcp + (size_t)kc * 663552 + (size_t)gm * 256 + wv * 64 + l15;
#pragma unroll
      for (int nf = 0; nf < 4; ++nf)
#pragma unroll
        for (int r = 0; r < 4; ++r)
          dst[(size_t)r * 256 + nf * 16] = __float2half(acc[mf][nf][r]);
    }
  }
}

// ---------------- fused transpose-reduce-squash: pcp(16 fp16 slices) -> u2 ----------------
__global__ __launch_bounds__(256) void k_rs(const __half* __restrict__ pcp,
                                            const float* __restrict__ pcb,
                                            float* __restrict__ u2) {
  __shared__ float tile[81 * 17];
  int b = blockIdx.x;    // 32
  int cog = blockIdx.y;  // 16
  int c0 = cog * 16;
  int t = threadIdx.x;

  for (int e = t; e < 1296; e += 256) {
    int p = e >> 4, col = e & 15;
    const __half* base = pcp + (size_t)(b * 81 + p) * 256 + c0 + col;
    float s = 0.f;
#pragma unroll
    for (int c = 0; c < 16; ++c) s += __half2float(base[(size_t)c * 663552]);
    tile[p * 17 + col] = pcb[c0 + col] + s * 0.015625f;  // /64 (W x64)
  }
  __syncthreads();

  if (t < 162) {
    float v[8];
    float sq = 0.f;
#pragma unroll
    for (int i = 0; i < 8; ++i) {
      int g = t * 8 + i;
      int col = g / 81, p = g - col * 81;
      v[i] = tile[p * 17 + col];
      sq += v[i] * v[i];
    }
    float sc = (sq / (1.f + sq)) / sqrtf(sq + 1e-8f);
    int n = cog * 162 + t;
    float4* dst = (float4*)(u2 + ((size_t)b * 2592 + n) * 8);
    dst[0] = make_float4(v[0] * sc, v[1] * sc, v[2] * sc, v[3] * sc);
    dst[1] = make_float4(v[4] * sc, v[5] * sc, v[6] * sc, v[7] * sc);
  }
}

// ---------------- routing kernel A3 (fp8 MFMA, o-split x3): E + partial den ----------------
__global__ __launch_bounds__(128) void k_A3(const unsigned char* __restrict__ Wq,
                                            const float* __restrict__ u2,
                                            const unsigned char* __restrict__ vq,
                                            __half* __restrict__ cT,
                                            float* __restrict__ den) {
  int nb = blockIdx.x;   // 648
  int ch = blockIdx.y;   // 3
  int o0 = ch * 34;
  int t = threadIdx.x, wv = t >> 6, lane = t & 63;
  int l15 = lane & 15, g = lane >> 4;
  int n0 = nb * 4 + 2 * wv;
  int nl = g >> 1, ih = (g & 1) * 4;

  float4 u0 = *(const float4*)(u2 + (((size_t)l15 * 2592 + n0 + nl) * 8 + ih));
  float4 u1 = *(const float4*)(u2 + (((size_t)(l15 + 16) * 2592 + n0 + nl) * 8 + ih));

  int nlA = l15 >> 3, iA = l15 & 7;
  const unsigned char* Ap = Wq + (((size_t)(n0 + nlA)) * 8 + iA) * 16 + (g & 1) * 8 +
                            (size_t)o0 * 331776;
  const unsigned char* B0p = vq + (size_t)l15 * 16 + (g & 1) * 8 + (size_t)o0 * 512;
  bool act = (g < 2);

  float den0 = 0.f, den1 = 0.f;
#pragma unroll 2
  for (int oo = 0; oo < 34; ++oo) {
    i64 a = 0, b0 = 0, b1 = 0;
    if (act) {
      a  = *(const i64*)(Ap + (size_t)oo * 331776);
      b0 = *(const i64*)(B0p + (size_t)oo * 512);
      b1 = *(const i64*)(B0p + (size_t)oo * 512 + 256);
    }
    f32x4 d0 = {0.f, 0.f, 0.f, 0.f}, d1 = {0.f, 0.f, 0.f, 0.f};
    d0 = __builtin_amdgcn_mfma_f32_16x16x32_fp8_fp8(a, b0, d0, 0, 0, 0);
    d1 = __builtin_amdgcn_mfma_f32_16x16x32_fp8_fp8(a, b1, d1, 0, 0, 0);
    float p0 = d0[0] * u0.x + d0[1] * u0.y + d0[2] * u0.z + d0[3] * u0.w;
    float p1 = d1[0] * u1.x + d1[1] * u1.y + d1[2] * u1.z + d1[3] * u1.w;
    p0 += __shfl_xor(p0, 16);
    p1 += __shfl_xor(p1, 16);
    p0 *= 1.52587890625e-05f;  // / (64 * 1024)
    p1 *= 1.52587890625e-05f;
    float e0 = __expf(p0), e1 = __expf(p1);
    den0 += e0; den1 += e1;
    if ((g & 1) == 0) {
      __half* dst = cT + ((size_t)(o0 + oo) * 2592 + n0 + nl) * 32 + l15;
      dst[0]  = __float2half(e0);
      dst[16] = __float2half(e1);
    }
  }
  if ((g & 1) == 0) {
    atomicAdd(den + (n0 + nl) * 32 + l15, den0);
    atomicAdd(den + (n0 + nl) * 32 + l15 + 16, den1);
  }
}

// ---------------- routing kernel B (fp8 MFMA): s = sum (E/den)*xhat ----------------
__device__ __forceinline__ i64 cu_pack8(float c, float4 a, float4 b) {
  union { unsigned u[2]; i64 v; } r;
  r.u[0] = fp8pair(c * a.x, c * a.y) | (fp8pair(c * a.z, c * a.w) << 16);
  r.u[1] = fp8pair(c * b.x, c * b.y) | (fp8pair(c * b.z, c * b.w) << 16);
  return r.v;
}

template <bool HASC>
__global__ __launch_bounds__(256) void k_B3(const unsigned char* __restrict__ Wq2,
                                            const float* __restrict__ u2,
                                            const __half* __restrict__ cT,
                                            const float* __restrict__ den,
                                            float* __restrict__ s) {
  int o = blockIdx.x, kc = blockIdx.y;  // (102, 12)
  int t = threadIdx.x, lane = t & 63, wv = t >> 6;
  int l15 = lane & 15, h = lane >> 4;

  f32x4 acc0 = {0.f, 0.f, 0.f, 0.f}, acc1 = {0.f, 0.f, 0.f, 0.f};

#pragma unroll 1
  for (int st = wv; st < 54; st += 4) {
    int n = kc * 216 + st * 4 + h;
    i64 aq = *(const i64*)(Wq2 + (((size_t)o * 2592 + n) * 16 + l15) * 8);

    const float4* u0p = (const float4*)(u2 + ((size_t)l15 * 2592 + n) * 8);
    float4 u0a = u0p[0], u0b = u0p[1];
    const float4* u1p = (const float4*)(u2 + ((size_t)(l15 + 16) * 2592 + n) * 8);
    float4 u1a = u1p[0], u1b = u1p[1];

    float c0 = 16.0f, c1 = 16.0f;
    if (HASC) {
      const __half* cp = cT + ((size_t)o * 2592 + n) * 32;
      float i0 = rcpf(den[n * 32 + l15]);
      float i1 = rcpf(den[n * 32 + l15 + 16]);
      c0 = 16.0f * __half2float(cp[l15]) * i0;
      c1 = 16.0f * __half2float(cp[l15 + 16]) * i1;
    }
    i64 b0 = cu_pack8(c0, u0a, u0b);
    i64 b1 = cu_pack8(c1, u1a, u1b);

    acc0 = __builtin_amdgcn_mfma_f32_16x16x32_fp8_fp8(aq, b0, acc0, 0, 0, 0);
    acc1 = __builtin_amdgcn_mfma_f32_16x16x32_fp8_fp8(aq, b1, acc1, 0, 0, 0);
  }

#pragma unroll
  for (int r = 0; r < 4; ++r) {
    atomicAdd(s + ((size_t)l15 * 102 + o) * 16 + h * 4 + r, acc0[r]);
    atomicAdd(s + ((size_t)(l15 + 16) * 102 + o) * 16 + h * 4 + r, acc1[r]);
  }
}

// ---------------- squash v; optional fp8 vsum; optional S re-zero + den zero ----------------
__global__ void k_R(const float* __restrict__ s, float scale,
                    float* __restrict__ vout, const float* __restrict__ addin,
                    unsigned char* __restrict__ vsq, float* __restrict__ szero,
                    float* __restrict__ dzero) {
  int t = blockIdx.x * 256 + threadIdx.x;  // grid 13*256 = 3328
  if (dzero) {
    for (int i = t; i < 82944; i += 3328) dzero[i] = 0.f;
  }
  if (t >= 3264) return;
  const float* sp = s + t * 16;
  float r[16];
  float sq = 0.f;
#pragma unroll
  for (int d = 0; d < 16; ++d) {
    r[d] = sp[d] * scale;
    sq += r[d] * r[d];
  }
  if (szero) {
#pragma unroll
    for (int d = 0; d < 16; ++d) szero[t * 16 + d] = 0.f;
  }
  float sc = (sq / (1.f + sq)) / sqrtf(sq + 1e-8f);
  float vv[16];
#pragma unroll
  for (int d = 0; d < 16; ++d) {
    vv[d] = r[d] * sc;
    vout[t * 16 + d] = vv[d];
  }
  if (vsq) {
    int b = t / 102, o = t - b * 102;
    float w[16];
#pragma unroll
    for (int d = 0; d < 16; ++d)
      w[d] = (addin ? (addin[t * 16 + d] + vv[d]) : vv[d]) * 1024.f;
    unsigned words[4];
#pragma unroll
    for (int q = 0; q < 4; ++q)
      words[q] = fp8pair(w[4 * q], w[4 * q + 1]) | (fp8pair(w[4 * q + 2], w[4 * q + 3]) << 16);
    *(uint4*)(vsq + ((size_t)o * 32 + b) * 16) =
        make_uint4(words[0], words[1], words[2], words[3]);
  }
}

// ---------------- fused fc1+fc2: block = bq (4 batch items), h1 in LDS ----------------
__global__ __launch_bounds__(512) void k_fc12(const float* __restrict__ v2,
                                              const int* __restrict__ tgt,
                                              const float* __restrict__ w1,
                                              const float* __restrict__ b1,
                                              const float* __restrict__ w2,
                                              const float* __restrict__ b2,
                                              float* __restrict__ h2T) {
  __shared__ float h1s[4][512];
  int bq = blockIdx.x;  // 8
  int t = threadIdx.x;  // 512
#pragma unroll
  for (int bi = 0; bi < 4; ++bi) {
    int b = bq * 4 + bi;
    int tb = tgt[b];
    float acc = b1[t];
    const float* vv = v2 + (b * 102 + tb) * 16;
    const float* wr = w1 + (tb * 16) * 512 + t;
#pragma unroll
    for (int d = 0; d < 16; ++d) acc += vv[d] * wr[d * 512];
    h1s[bi][t] = fmaxf(acc, 0.f);
  }
  __syncthreads();
  float a0[4], a1[4];
#pragma unroll
  for (int bi = 0; bi < 4; ++bi) { a0[bi] = b2[t]; a1[bi] = b2[t + 512]; }
  for (int k = 0; k < 512; ++k) {
    float w0 = w2[k * 1024 + t], w1v = w2[k * 1024 + t + 512];
#pragma unroll
    for (int bi = 0; bi < 4; ++bi) {
      float h = h1s[bi][k];
      a0[bi] += h * w0;
      a1[bi] += h * w1v;
    }
  }
  float4 o0, o1;
  o0.x = fmaxf(a0[0], 0.f); o0.y = fmaxf(a0[1], 0.f);
  o0.z = fmaxf(a0[2], 0.f); o0.w = fmaxf(a0[3], 0.f);
  o1.x = fmaxf(a1[0], 0.f); o1.y = fmaxf(a1[1], 0.f);
  o1.z = fmaxf(a1[2], 0.f); o1.w = fmaxf(a1[3], 0.f);
  *(float4*)(h2T + t * 32 + bq * 4) = o0;
  *(float4*)(h2T + (t + 512) * 32 + bq * 4) = o1;
}

__global__ void k_fc3a(const float* __restrict__ h2T, const float* __restrict__ w3,
                       float* __restrict__ p) {
  int j = blockIdx.x * 128 + threadIdx.x;
  int ky = blockIdx.y;
  float acc[32];
#pragma unroll
  for (int i = 0; i < 32; ++i) acc[i] = 0.f;
  int k0 = ky * 256;
  for (int k = k0; k < k0 + 256; ++k) {
    float wv = w3[(size_t)k * 37632 + j];
    const float4* hp = (const float4*)(h2T + k * 32);
#pragma unroll
    for (int q = 0; q < 8; ++q) {
      float4 h = hp[q];
      acc[q * 4 + 0] += h.x * wv; acc[q * 4 + 1] += h.y * wv;
      acc[q * 4 + 2] += h.z * wv; acc[q * 4 + 3] += h.w * wv;
    }
  }
#pragma unroll
  for (int i = 0; i < 32; ++i)
    p[((size_t)ky * 32 + i) * 37632 + j] = acc[i];
}

__global__ void k_fc3b(const float* __restrict__ p, const float* __restrict__ b3,
                       float* __restrict__ out) {
  int j = blockIdx.x * 256 + threadIdx.x;
  float bv = b3[j];
#pragma unroll 1
  for (int b = 0; b < 32; ++b) {
    float s = bv + p[(size_t)b * 37632 + j] + p[(size_t)(32 + b) * 37632 + j] +
              p[(size_t)(64 + b) * 37632 + j] + p[(size_t)(96 + b) * 37632 + j];
    out[52224 + (size_t)b * 37632 + j] = 1.0f / (1.0f + __expf(-s));
  }
}

// ---------------- host ----------------
extern "C" void kernel_launch(void* const* d_in, const int* in_sizes, int n_in,
                              void* d_out, int out_size, void* d_ws, size_t ws_size,
                              hipStream_t stream) {
  const float* x       = (const float*)d_in[0];
  const int*   targets = (const int*)d_in[1];
  const float* conv1_w = (const float*)d_in[2];
  const float* conv1_b = (const float*)d_in[3];
  const float* pc_w    = (const float*)d_in[4];
  const float* pc_b    = (const float*)d_in[5];
  const float* W       = (const float*)d_in[6];
  const float* fc1_w   = (const float*)d_in[7];
  const float* fc1_b   = (const float*)d_in[8];
  const float* fc2_w   = (const float*)d_in[9];
  const float* fc2_b   = (const float*)d_in[10];
  const float* fc3_w   = (const float*)d_in[11];
  const float* fc3_b   = (const float*)d_in[12];
  float* out = (float*)d_out;
  float* ws = (float*)d_ws;

  unsigned short* FEAT2 = (unsigned short*)(ws + OFF_FEAT);
  unsigned short* C1WB = (unsigned short*)(ws + OFF_C1WT);
  unsigned char* PCWQ = (unsigned char*)(ws + OFF_PCWQ);
  __half* PCP = (__half*)(ws + OFF_PCP);
  unsigned char* WQ2 = (unsigned char*)(ws + OFF_WQ2);
  unsigned char* WQ  = (unsigned char*)(ws + OFF_WQ);
  float* U2   = ws + OFF_U2;
  __half* CT  = (__half*)(ws + OFF_CT);
  float* DEN  = ws + OFF_DEN;
  float* S    = ws + OFF_S;
  float* V0   = ws + OFF_V0;
  float* V1   = ws + OFF_V1;
  unsigned char* VSQ = (unsigned char*)(ws + OFF_VSQ);
  float* H2T  = ws + OFF_H2T;
  float* FC3P = ws + OFF_FC3P;

  // conv1 pack (consumed by k_c1m)
  k_pack0<<<dim3(256), 128, 0, stream>>>(conv1_w, C1WB);

  // conv1 (bf16 MFMA) ++ pc_w pack fused
  k_c1m<<<dim3(2432), 256, 0, stream>>>(x, C1WB, conv1_b, FEAT2, pc_w, PCWQ);

  // pc conv (fp8 MFMA) ++ W pack + S zero fused
  k_pc4<<<dim3(4838), 256, 0, stream>>>(FEAT2, PCWQ, PCP, W, WQ2, WQ, S);
  k_rs<<<dim3(32, 16), 256, 0, stream>>>(PCP, pc_b, U2);

  // ---- routing ---- (scales: W x64, cu x16 -> /1024; vq x1024 -> logits /65536)
  k_B3<false><<<dim3(102, 12), 256, 0, stream>>>(WQ2, U2, nullptr, nullptr, S);
  k_R<<<dim3(13), 256, 0, stream>>>(S, 1.0f / (102.0f * 1024.0f), V0, nullptr, VSQ, S, DEN);

  k_A3<<<dim3(648, 3), 128, 0, stream>>>(WQ, U2, VSQ, CT, DEN);
  k_B3<true><<<dim3(102, 12), 256, 0, stream>>>(WQ2, U2, CT, DEN, S);
  k_R<<<dim3(13), 256, 0, stream>>>(S, 1.0f / 1024.0f, V1, V0, VSQ, S, DEN);  // vsq = v0+v1

  k_A3<<<dim3(648, 3), 128, 0, stream>>>(WQ, U2, VSQ, CT, DEN);
  k_B3<true><<<dim3(102, 12), 256, 0, stream>>>(WQ2, U2, CT, DEN, S);
  k_R<<<dim3(13), 256, 0, stream>>>(S, 1.0f / 1024.0f, out, nullptr, nullptr, nullptr, nullptr);

  // ---- reconstruction ----
  k_fc12<<<dim3(8), 512, 0, stream>>>(out, targets, fc1_w, fc1_b, fc2_w, fc2_b, H2T);
  k_fc3a<<<dim3(294, 4), 128, 0, stream>>>(H2T, fc3_w, FC3P);
  k_fc3b<<<dim3(147), 256, 0, stream>>>(FC3P, fc3_b, out);
}